// Round 15
// baseline (331.855 us; speedup 1.0000x reference)
//
#include <hip/hip_runtime.h>
#include <hip/hip_bf16.h>
#include <stdint.h>

typedef __bf16 bf16_t;
typedef __attribute__((ext_vector_type(8))) __bf16 bf16x8;
typedef __attribute__((ext_vector_type(4))) float f32x4;
typedef __attribute__((ext_vector_type(8))) unsigned short u16x8;
typedef __attribute__((ext_vector_type(4))) unsigned int u32x4;

#define S_LEN 2048
#define DIM   4096
#define QKVN  6144
#define NHEAD 32
#define HDIM  128

typedef __attribute__((address_space(1))) unsigned int as1_u32;
typedef __attribute__((address_space(3))) unsigned int as3_u32;

__device__ __forceinline__ unsigned short f2bf(float f) {
  unsigned u = __builtin_bit_cast(unsigned, f);
  u += 0x7fffu + ((u >> 16) & 1u);
  return (unsigned short)(u >> 16);
}

__device__ __forceinline__ void gload_lds16(const void* g, void* l) {
  __builtin_amdgcn_global_load_lds(
      (as1_u32*)(unsigned long long)(uintptr_t)g,
      (as3_u32*)(unsigned int)(uintptr_t)l,
      16, 0, 0);
}

// cvt two float4 -> one bf16x8 word-vector via v_cvt_pk_bf16_f32 (RNE).
__device__ __forceinline__ u32x4 cvt8(const float4& lo, const float4& hi) {
  unsigned q0, q1, q2, q3;
  asm("v_cvt_pk_bf16_f32 %0, %1, %2" : "=v"(q0) : "v"(lo.x), "v"(lo.y));
  asm("v_cvt_pk_bf16_f32 %0, %1, %2" : "=v"(q1) : "v"(lo.z), "v"(lo.w));
  asm("v_cvt_pk_bf16_f32 %0, %1, %2" : "=v"(q2) : "v"(hi.x), "v"(hi.y));
  asm("v_cvt_pk_bf16_f32 %0, %1, %2" : "=v"(q3) : "v"(hi.z), "v"(hi.w));
  u32x4 r = {q0, q1, q2, q3};
  return r;
}

// f32->bf16 conversion for x only (weights are converted in-GEMM now).
__global__ __launch_bounds__(256) void cvt_x(const float* __restrict__ x,
                                             ushort4* __restrict__ xb) {
  const long N0 = 2097152;  // 2048*4096/4
  long idx = (long)blockIdx.x * 256 + threadIdx.x;
  long stride = (long)gridDim.x * 256;
  for (long i = idx; i < N0; i += stride) {
    float4 v = ((const float4*)x)[i];
    ushort4 r;
    r.x = f2bf(v.x); r.y = f2bf(v.y); r.z = f2bf(v.z); r.w = f2bf(v.w);
    xb[i] = r;
  }
}

// Shared swizzled LDS fragment read: chunk ^= (row&7), both sides.
__device__ __forceinline__ bf16x8 fld(const char* half, int row, int chunk) {
  return *(const bf16x8*)(half + row * 128 + ((chunk ^ (row & 7)) << 4));
}

// ---- 256x192 4-phase GEMM, BK=64, 8 waves (2M x 4N); B read as f32 -----
// A bf16 staged via gload_lds (3 buf x 32K). B = f32 weights (wq/wk/wv),
// converted in-staging: P2 does {vmcnt(4) [drains A(t+1)+Bf32(t+1)];
// cvt_pk + 3x ds_write_b128 (swizzled) -> B(t+1) buf; issue Bf32(t+2)
// 6x global_load_dwordx4; lgkm(0) BEFORE barrier (write visibility)}.
// FIFO ledger: end-of-tile outstanding = {A(t+2):4, Bf32(t+2):6}.
__global__ __launch_bounds__(512, 2) void gemm8q(const bf16_t* __restrict__ A,
                                                 const float* __restrict__ Wq,
                                                 const float* __restrict__ Wk,
                                                 const float* __restrict__ Wv,
                                                 unsigned short* __restrict__ C,
                                                 int M, int N, int K, int nxt) {
  __shared__ char lds[147456];   // A 3x32K @0; B 2x24K @98304
  const int tid = threadIdx.x;
  const int lane = tid & 63, w = tid >> 6;
  const int wm = w >> 2, wn = w & 3;       // 2 M-waves x 4 N-waves
  const int lg = lane >> 4, lr = lane & 15;
  const int nwg = gridDim.x;
  const int orig = blockIdx.x;
  const int wgid = (orig & 7) * (nwg >> 3) + (orig >> 3);  // nwg % 8 == 0
  const int bx = wgid % nxt, by = wgid / nxt;
  const long rowA = (long)by * 256;
  const long rowB = (long)bx * 192;

  f32x4 acc[8][3];
  const f32x4 z4 = {0.f, 0.f, 0.f, 0.f};
#pragma unroll
  for (int i = 0; i < 8; ++i)
#pragma unroll
    for (int j = 0; j < 3; ++j) acc[i][j] = z4;

  const int r0 = tid >> 3, sl = tid & 7;
  const long xo  = (long)((sl ^ (r0 & 7)) << 3);
  const long aof = (rowA + r0) * (long)K + xo;
  const long j1  = (long)64 * K;
  const long h1  = (long)128 * K;
  const int ld0 = tid * 16, ld1 = (tid + 512) * 16;

  // per-thread B staging: 3 chunks c = tid + i*512; row = c>>3, slot = c&7.
  const float* bsrc[3];
  int ldsw[3];
#pragma unroll
  for (int i = 0; i < 3; ++i) {
    int c = tid + i * 512;
    int row = c >> 3, s = c & 7;
    long grow = rowB + row;
    const float* base = (grow < 4096) ? (Wq + grow * (long)K)
                       : (grow < 5120) ? (Wk + (grow - 4096) * (long)K)
                                       : (Wv + (grow - 5120) * (long)K);
    bsrc[i] = base + s * 8;
    ldsw[i] = row * 128 + ((s ^ (row & 7)) << 4);
  }

#define QSTG_A(K0, HALF, BUF3)                                                 \
  { char* hp = lds + (BUF3) * 32768 + (HALF) * 16384;                          \
    gload_lds16(A + aof + (HALF) * h1 + (K0),      hp + ld0);                  \
    gload_lds16(A + aof + (HALF) * h1 + j1 + (K0), hp + ld1); }
#define QLOAD_B(K0)                                                            \
  _Pragma("unroll")                                                            \
  for (int i = 0; i < 3; ++i) {                                                \
    blo[i] = *(const float4*)(bsrc[i] + (K0));                                 \
    bhi[i] = *(const float4*)(bsrc[i] + (K0) + 4);                             \
  }
#define QWRITE_B(DB)                                                           \
  { char* bw = lds + 98304 + (DB) * 24576;                                     \
    _Pragma("unroll")                                                          \
    for (int i = 0; i < 3; ++i) *(u32x4*)(bw + ldsw[i]) = cvt8(blo[i], bhi[i]); }

  const int nt = K >> 6;
  const int brow = wn * 48;
  float4 blo[3], bhi[3];

  // prologue: A(0)->buf0, A(1)->buf1, Bf32(0); drain; write B(0); Bf32(1).
  QSTG_A(0, 0, 0); QSTG_A(0, 1, 0);
  QSTG_A(64, 0, 1); QSTG_A(64, 1, 1);
  QLOAD_B(0);
  asm volatile("s_waitcnt vmcnt(0)" ::: "memory");
  QWRITE_B(0);
  QLOAD_B(64);
  asm volatile("s_waitcnt lgkmcnt(0)" ::: "memory");
  __builtin_amdgcn_s_barrier();

  bf16x8 af[8][2], bf_[3][2];

  for (int t = 0; t < nt; ++t) {
    const int a3 = t % 3, s3 = (t + 2) % 3;
    const char* Ah = lds + a3 * 32768 + wm * 16384;
    const char* Br = lds + 98304 + (t & 1) * 24576;
    const int k2 = (t + 2) << 6;
    // ---- P0: read A m0-1 + B all; stage A.h0(t+2) ----
#pragma unroll
    for (int m = 0; m < 2; ++m) {
      af[m][0] = fld(Ah, m * 16 + lr, lg);
      af[m][1] = fld(Ah, m * 16 + lr, 4 + lg);
    }
#pragma unroll
    for (int n = 0; n < 3; ++n) {
      bf_[n][0] = fld(Br, brow + n * 16 + lr, lg);
      bf_[n][1] = fld(Br, brow + n * 16 + lr, 4 + lg);
    }
    if (t + 2 < nt) QSTG_A(k2, 0, s3);
    __builtin_amdgcn_s_barrier();
    asm volatile("s_waitcnt lgkmcnt(0)" ::: "memory");
    __builtin_amdgcn_sched_barrier(0);
    __builtin_amdgcn_s_setprio(1);
#pragma unroll
    for (int m = 0; m < 2; ++m)
#pragma unroll
      for (int n = 0; n < 3; ++n) {
        acc[m][n] = __builtin_amdgcn_mfma_f32_16x16x32_bf16(af[m][0], bf_[n][0], acc[m][n], 0, 0, 0);
        acc[m][n] = __builtin_amdgcn_mfma_f32_16x16x32_bf16(af[m][1], bf_[n][1], acc[m][n], 0, 0, 0);
      }
    __builtin_amdgcn_s_setprio(0);
    __builtin_amdgcn_s_barrier();
    // ---- P1: read A m2-3; stage A.h1(t+2) ----
#pragma unroll
    for (int m = 2; m < 4; ++m) {
      af[m][0] = fld(Ah, m * 16 + lr, lg);
      af[m][1] = fld(Ah, m * 16 + lr, 4 + lg);
    }
    if (t + 2 < nt) QSTG_A(k2, 1, s3);
    __builtin_amdgcn_s_barrier();
    asm volatile("s_waitcnt lgkmcnt(0)" ::: "memory");
    __builtin_amdgcn_sched_barrier(0);
    __builtin_amdgcn_s_setprio(1);
#pragma unroll
    for (int m = 2; m < 4; ++m)
#pragma unroll
      for (int n = 0; n < 3; ++n) {
        acc[m][n] = __builtin_amdgcn_mfma_f32_16x16x32_bf16(af[m][0], bf_[n][0], acc[m][n], 0, 0, 0);
        acc[m][n] = __builtin_amdgcn_mfma_f32_16x16x32_bf16(af[m][1], bf_[n][1], acc[m][n], 0, 0, 0);
      }
    __builtin_amdgcn_s_setprio(0);
    __builtin_amdgcn_s_barrier();
    // ---- P2: read A m4-5; cvt+write B(t+1); issue Bf32(t+2) ----
#pragma unroll
    for (int m = 4; m < 6; ++m) {
      af[m][0] = fld(Ah, m * 16 + lr, lg);
      af[m][1] = fld(Ah, m * 16 + lr, 4 + lg);
    }
    if (t + 1 < nt) {
      if (t + 2 < nt) { asm volatile("s_waitcnt vmcnt(4)" ::: "memory"); }
      else            { asm volatile("s_waitcnt vmcnt(0)" ::: "memory"); }
      QWRITE_B((t + 1) & 1);
    }
    if (t + 2 < nt) QLOAD_B(k2);
    asm volatile("s_waitcnt lgkmcnt(0)" ::: "memory");   // reads+writes drained
    __builtin_amdgcn_sched_barrier(0);
    __builtin_amdgcn_s_barrier();
    __builtin_amdgcn_s_setprio(1);
#pragma unroll
    for (int m = 4; m < 6; ++m)
#pragma unroll
      for (int n = 0; n < 3; ++n) {
        acc[m][n] = __builtin_amdgcn_mfma_f32_16x16x32_bf16(af[m][0], bf_[n][0], acc[m][n], 0, 0, 0);
        acc[m][n] = __builtin_amdgcn_mfma_f32_16x16x32_bf16(af[m][1], bf_[n][1], acc[m][n], 0, 0, 0);
      }
    __builtin_amdgcn_s_setprio(0);
    __builtin_amdgcn_s_barrier();
    // ---- P3: read A m6-7; MFMA ----
#pragma unroll
    for (int m = 6; m < 8; ++m) {
      af[m][0] = fld(Ah, m * 16 + lr, lg);
      af[m][1] = fld(Ah, m * 16 + lr, 4 + lg);
    }
    __builtin_amdgcn_s_barrier();
    asm volatile("s_waitcnt lgkmcnt(0)" ::: "memory");
    __builtin_amdgcn_sched_barrier(0);
    __builtin_amdgcn_s_setprio(1);
#pragma unroll
    for (int m = 6; m < 8; ++m)
#pragma unroll
      for (int n = 0; n < 3; ++n) {
        acc[m][n] = __builtin_amdgcn_mfma_f32_16x16x32_bf16(af[m][0], bf_[n][0], acc[m][n], 0, 0, 0);
        acc[m][n] = __builtin_amdgcn_mfma_f32_16x16x32_bf16(af[m][1], bf_[n][1], acc[m][n], 0, 0, 0);
      }
    __builtin_amdgcn_s_setprio(0);
    __builtin_amdgcn_s_barrier();
  }
#undef QSTG_A
#undef QLOAD_B
#undef QWRITE_B

  const long crow = rowA + wm * 128;
  const long ccol = rowB + wn * 48;
#pragma unroll
  for (int mf = 0; mf < 8; ++mf)
#pragma unroll
    for (int j = 0; j < 4; ++j) {
      long row = crow + mf * 16 + lg * 4 + j;
      unsigned short* cp = C + row * N + ccol + lr;
#pragma unroll
      for (int nf = 0; nf < 3; ++nf) cp[nf * 16] = f2bf(acc[mf][nf][j]);
    }
}

// ---- 256x128 2-phase GEMM, BK=64, 8 waves; B = f32 weight (wo) ----------
// Same in-staging cvt pattern: P1 does vmcnt(4); cvt+2x ds_write_b128;
// issue Bf32(t+2) 4x dwordx4; lgkm(0) before barrier.
__global__ __launch_bounds__(512, 2) void gemm2p(const bf16_t* __restrict__ A,
                                                 const float* __restrict__ W,
                                                 float* __restrict__ C,
                                                 int M, int N, int K, int nxt) {
  __shared__ char lds[131072];   // A 3x32K @0; B 2x16K @98304
  const int tid = threadIdx.x;
  const int lane = tid & 63, w = tid >> 6;
  const int wm = w >> 1, wn = w & 1;       // 4 M-waves x 2 N-waves, 64x64
  const int lg = lane >> 4, lr = lane & 15;
  const int nwg = gridDim.x;
  const int orig = blockIdx.x;
  const int wgid = (orig & 7) * (nwg >> 3) + (orig >> 3);  // nwg % 8 == 0
  const int bx = wgid % nxt, by = wgid / nxt;
  const long rowA = (long)by * 256;
  const long rowB = (long)bx * 128;

  f32x4 acc[4][4];
  const f32x4 z4 = {0.f, 0.f, 0.f, 0.f};
#pragma unroll
  for (int i = 0; i < 4; ++i)
#pragma unroll
    for (int j = 0; j < 4; ++j) acc[i][j] = z4;

  const int r0 = tid >> 3, sl = tid & 7;
  const long xo  = (long)((sl ^ (r0 & 7)) << 3);
  const long aof = (rowA + r0) * (long)K + xo;
  const long r64 = (long)64 * K;

  const float* bsrc[2];
  int ldsw[2];
#pragma unroll
  for (int i = 0; i < 2; ++i) {
    int c = tid + i * 512;
    int row = c >> 3, s = c & 7;
    bsrc[i] = W + (rowB + row) * (long)K + s * 8;
    ldsw[i] = row * 128 + ((s ^ (row & 7)) << 4);
  }

#define PSTG_A(K0, BUF)                                                        \
  { char* ap = lds + (BUF) * 32768;                                            \
    gload_lds16(A + aof + (K0),           ap + tid * 16);                      \
    gload_lds16(A + aof + r64 + (K0),     ap + (tid + 512) * 16);              \
    gload_lds16(A + aof + 2 * r64 + (K0), ap + (tid + 1024) * 16);             \
    gload_lds16(A + aof + 3 * r64 + (K0), ap + (tid + 1536) * 16); }
#define PLOAD_B(K0)                                                            \
  _Pragma("unroll")                                                            \
  for (int i = 0; i < 2; ++i) {                                                \
    blo[i] = *(const float4*)(bsrc[i] + (K0));                                 \
    bhi[i] = *(const float4*)(bsrc[i] + (K0) + 4);                             \
  }
#define PWRITE_B(DB)                                                           \
  { char* bw = lds + 98304 + (DB) * 16384;                                     \
    _Pragma("unroll")                                                          \
    for (int i = 0; i < 2; ++i) *(u32x4*)(bw + ldsw[i]) = cvt8(blo[i], bhi[i]); }

  const int nt = K >> 6;
  float4 blo[2], bhi[2];

  PSTG_A(0, 0); PSTG_A(64, 1);
  PLOAD_B(0);
  asm volatile("s_waitcnt vmcnt(0)" ::: "memory");
  PWRITE_B(0);
  PLOAD_B(64);
  asm volatile("s_waitcnt lgkmcnt(0)" ::: "memory");
  __builtin_amdgcn_s_barrier();

  bf16x8 af[4][2], bf_[4][2];

  for (int t = 0; t < nt; ++t) {
    const int b3 = t % 3, s3 = (t + 2) % 3;
    const char* Ab = lds + b3 * 32768;
    const char* Bb = lds + 98304 + (t & 1) * 16384;
    const int arow = wm * 64, brow = wn * 64;
    const int k2 = (t + 2) << 6;
    // ---- P0: read A all + B n0-1; stage A(t+2) ----
#pragma unroll
    for (int m = 0; m < 4; ++m) {
      af[m][0] = fld(Ab, arow + m * 16 + lr, lg);
      af[m][1] = fld(Ab, arow + m * 16 + lr, 4 + lg);
    }
#pragma unroll
    for (int n = 0; n < 2; ++n) {
      bf_[n][0] = fld(Bb, brow + n * 16 + lr, lg);
      bf_[n][1] = fld(Bb, brow + n * 16 + lr, 4 + lg);
    }
    if (t + 2 < nt) PSTG_A(k2, s3);
    __builtin_amdgcn_s_barrier();
    asm volatile("s_waitcnt lgkmcnt(0)" ::: "memory");
    __builtin_amdgcn_sched_barrier(0);
    __builtin_amdgcn_s_setprio(1);
#pragma unroll
    for (int m = 0; m < 4; ++m)
#pragma unroll
      for (int n = 0; n < 2; ++n) {
        acc[m][n] = __builtin_amdgcn_mfma_f32_16x16x32_bf16(af[m][0], bf_[n][0], acc[m][n], 0, 0, 0);
        acc[m][n] = __builtin_amdgcn_mfma_f32_16x16x32_bf16(af[m][1], bf_[n][1], acc[m][n], 0, 0, 0);
      }
    __builtin_amdgcn_s_setprio(0);
    __builtin_amdgcn_s_barrier();
    // ---- P1: read B n2-3; cvt+write B(t+1); issue Bf32(t+2) ----
#pragma unroll
    for (int n = 2; n < 4; ++n) {
      bf_[n][0] = fld(Bb, brow + n * 16 + lr, lg);
      bf_[n][1] = fld(Bb, brow + n * 16 + lr, 4 + lg);
    }
    if (t + 1 < nt) {
      if (t + 2 < nt) { asm volatile("s_waitcnt vmcnt(4)" ::: "memory"); }
      else            { asm volatile("s_waitcnt vmcnt(0)" ::: "memory"); }
      PWRITE_B((t + 1) & 1);
    }
    if (t + 2 < nt) PLOAD_B(k2);
    asm volatile("s_waitcnt lgkmcnt(0)" ::: "memory");
    __builtin_amdgcn_sched_barrier(0);
    __builtin_amdgcn_s_barrier();
    __builtin_amdgcn_s_setprio(1);
#pragma unroll
    for (int m = 0; m < 4; ++m)
#pragma unroll
      for (int n = 2; n < 4; ++n) {
        acc[m][n] = __builtin_amdgcn_mfma_f32_16x16x32_bf16(af[m][0], bf_[n][0], acc[m][n], 0, 0, 0);
        acc[m][n] = __builtin_amdgcn_mfma_f32_16x16x32_bf16(af[m][1], bf_[n][1], acc[m][n], 0, 0, 0);
      }
    __builtin_amdgcn_s_setprio(0);
    __builtin_amdgcn_s_barrier();
  }
#undef PSTG_A
#undef PLOAD_B
#undef PWRITE_B

  const long crow = rowA + wm * 64;
  const long ccol = rowB + wn * 64;
#pragma unroll
  for (int mf = 0; mf < 4; ++mf)
#pragma unroll
    for (int j = 0; j < 4; ++j) {
      long row = crow + mf * 16 + lg * 4 + j;
      float* cp = C + row * N + ccol + lr;
#pragma unroll
      for (int nf = 0; nf < 4; ++nf) cp[nf * 16] = acc[mf][nf][j];
    }
}

// Merged prep: blocks [0,1024) = V transpose; blocks [1024, 21504) = RoPE.
__global__ __launch_bounds__(256) void prep_kernel(bf16_t* __restrict__ qkv,
                                                   bf16_t* __restrict__ vT,
                                                   const float* __restrict__ cosb,
                                                   const float* __restrict__ sinb) {
  const int bid = blockIdx.x;
  if (bid < 1024) {
    const int kh = bid & 7;
    const int hd = threadIdx.x & 127;
    const int s0 = (bid >> 3) * 16 + (threadIdx.x >> 7) * 8;
    u16x8 v;
#pragma unroll
    for (int e = 0; e < 8; ++e)
      v[e] = *(const unsigned short*)(qkv + (long)(s0 + e) * QKVN + 5120 + kh * HDIM + hd);
    *(u16x8*)(vT + ((long)kh * HDIM + hd) * S_LEN + s0) = v;
  } else {
    int t = (bid - 1024) * 256 + threadIdx.x;
    int i  = t & 63;
    int sh = t >> 6;
    int hh = sh % 40;
    int s  = sh / 40;
    int col2 = (hh < 32) ? (hh * 64 + i) : (2048 + (hh - 32) * 64 + i);
    unsigned int* p = (unsigned int*)qkv + (long)s * (QKVN / 2) + col2;
    unsigned int v = *p;
    float tr = __builtin_bit_cast(float, (v & 0xffffu) << 16);
    float ti = __builtin_bit_cast(float, v & 0xffff0000u);
    float c  = cosb[s * 64 + i];
    float sn = sinb[s * 64 + i];
    float orr = tr * c - ti * sn;
    float oi  = tr * sn + ti * c;
    *p = (unsigned int)f2bf(orr) | ((unsigned int)f2bf(oi) << 16);
  }
}

// Flash attention (R14-verified): 128 q-rows/block, 8 waves, KVBLK=64,
// K/V double-buffered; per-lane plsum; __any-gated max reduce.
__global__ __launch_bounds__(512) void attn_kernel(const bf16_t* __restrict__ qkv,
                                                   const bf16_t* __restrict__ vT,
                                                   unsigned short* __restrict__ ob) {
  __shared__ bf16_t Kt[2][64 * 128];
  __shared__ bf16_t Vt[2][128 * 64];
  __shared__ bf16_t Pl[8 * 16 * 64];
  const int h  = blockIdx.x;
  const int qi = 15 - (int)blockIdx.y;
  const int qb = qi * 128;
  const int kh = h >> 2;
  const int tid = threadIdx.x, lane = tid & 63, w = tid >> 6;
  const int lg = lane >> 4, lr = lane & 15;
  const int qrow0 = qb + w * 16;

  bf16x8 qf[4];
  const bf16_t* qptr = qkv + (long)(qrow0 + lr) * QKVN + h * HDIM + lg * 8;
#pragma unroll
  for (int kk = 0; kk < 4; ++kk) qf[kk] = *(const bf16x8*)(qptr + kk * 32);

  const f32x4 z4 = {0.f, 0.f, 0.f, 0.f};
  f32x4 oacc[8];
#pragma unroll
  for (int c = 0; c < 8; ++c) oacc[c] = z4;
  float m[4]     = {-1e30f, -1e30f, -1e30f, -1e30f};
  float plsum[4] = {0.f, 0.f, 0.f, 0.f};

  char* PlB = (char*)Pl + w * 2048;
  const float SCL2 = 0.08838834764831845f * 1.44269504088896f;
  const int ntiles = 2 * qi + 2;
  const int wqmax = qrow0 + 15;

#define STAGE_KV(T, BUF)                                                       \
  {                                                                            \
    const int kvs = (T) * 64;                                                  \
    _Pragma("unroll")                                                          \
    for (int it = 0; it < 2; ++it) {                                           \
      int cch = tid + it * 512;                                                \
      int r = cch >> 4, c = cch & 15;                                          \
      gload_lds16(qkv + (long)(kvs + r) * QKVN + 4096 + kh * HDIM              \
                      + ((c ^ (r & 7)) * 8),                                   \
                  (char*)Kt[BUF] + cch * 16);                                  \
    }                                                                          \
    _Pragma("unroll")                                                          \
    for (int it = 0; it < 2; ++it) {                                           \
      int cch = tid + it * 512;                                                \
      int hd2 = cch >> 3, c = cch & 7;                                         \
      gload_lds16(vT + ((long)kh * HDIM + hd2) * S_LEN + kvs                   \
                      + ((c ^ (hd2 & 7)) * 8),                                 \
                  (char*)Vt[BUF] + cch * 16);                                  \
    }                                                                          \
  }

  STAGE_KV(0, 0);
  STAGE_KV(1, 1);
  asm volatile("s_waitcnt vmcnt(4)" ::: "memory");
  __builtin_amdgcn_s_barrier();

  for (int t = 0; t < ntiles; ++t) {
    const int kv0 = t * 64;
    const int d = t & 1;
    if (kv0 <= wqmax) {
      char* KtB = (char*)Kt[d];
      char* VtB = (char*)Vt[d];

      f32x4 sf[4];
#pragma unroll
      for (int f = 0; f < 4; ++f) {
        f32x4 a = z4;
        int n = f * 16 + lr;
        int rb = n * 256, sw = (n & 7) << 4;
#pragma unroll
        for (int kk = 0; kk < 4; ++kk) {
          bf16x8 kf = *(const bf16x8*)(KtB + rb + (((kk * 4 + lg) * 16) ^ sw));
          a = __builtin_amdgcn_mfma_f32_16x16x32_bf16(qf[kk], kf, a, 0, 0, 0);
        }
        sf[f] = a;
      }

      float sv[4][4], lmax[4];
      if (kv0 + 63 <= qrow0) {
#pragma unroll
        for (int j = 0; j < 4; ++j) {
#pragma unroll
          for (int f = 0; f < 4; ++f) sv[j][f] = sf[f][j] * SCL2;
          lmax[j] = fmaxf(fmaxf(sv[j][0], sv[j][1]), fmaxf(sv[j][2], sv[j][3]));
        }
      } else {
#pragma unroll
        for (int j = 0; j < 4; ++j) {
          int qrow = qrow0 + lg * 4 + j;
#pragma unroll
          for (int f = 0; f < 4; ++f) {
            float s = sf[f][j] * SCL2;
            if (kv0 + f * 16 + lr > qrow) s = -1e9f;
            sv[j][f] = s;
          }
          lmax[j] = fmaxf(fmaxf(sv[j][0], sv[j][1]), fmaxf(sv[j][2], sv[j][3]));
        }
      }
      float g = fmaxf(fmaxf(lmax[0] - m[0], lmax[1] - m[1]),
                      fmaxf(lmax[2] - m[2], lmax[3] - m[3]));
      if (__any(g > 0.f)) {
#pragma unroll
        for (int j = 0; j < 4; ++j) {
          float t0 = lmax[j];
          t0 = fmaxf(t0, __shfl_xor(t0, 1));
          t0 = fmaxf(t0, __shfl_xor(t0, 2));
          t0 = fmaxf(t0, __shfl_xor(t0, 4));
          t0 = fmaxf(t0, __shfl_xor(t0, 8));
          float mn = fmaxf(m[j], t0);
          float sc;
          asm("v_exp_f32 %0, %1" : "=v"(sc) : "v"(m[j] - mn));
          plsum[j] *= sc;
          m[j] = mn;
#pragma unroll
          for (int c = 0; c < 8; ++c) oacc[c][j] *= sc;
        }
      }
#pragma unroll
      for (int j = 0; j < 4; ++j) {
        float p[4];
#pragma unroll
        for (int f = 0; f < 4; ++f)
          asm("v_exp_f32 %0, %1" : "=v"(p[f]) : "v"(sv[j][f] - m[j]));
        plsum[j] += (p[0] + p[1]) + (p[2] + p[3]);
        int row = lg * 4 + j;
        int swp = (row & 7) << 4;
#pragma unroll
        for (int f = 0; f < 4; ++f)
          *(unsigned short*)(PlB + row * 128 + (((f * 16 + lr) * 2) ^ swp)) = f2bf(p[f]);
      }

      bf16x8 pfr[2];
#pragma unroll
      for (int kk = 0; kk < 2; ++kk)
        pfr[kk] = *(const bf16x8*)(PlB + lr * 128 + (((kk * 4 + lg) * 16) ^ ((lr & 7) << 4)));
#pragma unroll
      for (int c = 0; c < 8; ++c) {
        int hd = c * 16 + lr;
        int rb = hd * 128, sw = (hd & 7) << 4;
#pragma unroll
        for (int kk = 0; kk < 2; ++kk) {
          bf16x8 vf = *(const bf16x8*)(VtB + rb + (((kk * 4 + lg) * 16) ^ sw));
          oacc[c] = __builtin_amdgcn_mfma_f32_16x16x32_bf16(pfr[kk], vf, oacc[c], 0, 0, 0);
        }
      }
    }
    __builtin_amdgcn_s_barrier();
    if (t + 2 < ntiles) {
      STAGE_KV(t + 2, d);
      asm volatile("s_waitcnt vmcnt(4)" ::: "memory");
    } else {
      asm volatile("s_waitcnt vmcnt(0)" ::: "memory");
    }
    __builtin_amdgcn_s_barrier();
  }
#undef STAGE_KV

  float rl[4];
#pragma unroll
  for (int j = 0; j < 4; ++j) {
    float s = plsum[j];
    s += __shfl_xor(s, 1);
    s += __shfl_xor(s, 2);
    s += __shfl_xor(s, 4);
    s += __shfl_xor(s, 8);
    rl[j] = 1.f / s;
  }
#pragma unroll
  for (int c = 0; c < 8; ++c)
#pragma unroll
    for (int j = 0; j < 4; ++j) {
      long row = qrow0 + lg * 4 + j;
      ob[row * 4096 + h * 128 + c * 16 + lr] = f2bf(oacc[c][j] * rl[j]);
    }
}

extern "C" void kernel_launch(void* const* d_in, const int* in_sizes, int n_in,
                              void* d_out, int out_size, void* d_ws, size_t ws_size,
                              hipStream_t stream) {
  const float* x  = (const float*)d_in[0];
  const float* wq = (const float*)d_in[1];
  const float* wk = (const float*)d_in[2];
  const float* wv = (const float*)d_in[3];
  const float* wo = (const float*)d_in[4];
  const float* fc = (const float*)d_in[5];
  const float* fs = (const float*)d_in[6];

  char* ws = (char*)d_ws;
  bf16_t* xb  = (bf16_t*)(ws + 0);            // 2048x4096 (dead after gemm1)
  bf16_t* qkv = (bf16_t*)(ws + 100663296);    // 2048x6144
  bf16_t* ob  = (bf16_t*)(ws + 125829120);    // 2048x4096
  bf16_t* vT  = (bf16_t*)(ws + 33554432);     // 8x128x2048 (4 MB)

  cvt_x<<<1024, 256, 0, stream>>>(x, (ushort4*)xb);

  gemm8q<<<256, 512, 0, stream>>>(xb, wq, wk, wv, (unsigned short*)qkv,
                                  2048, 6144, 4096, 32);
  prep_kernel<<<21504, 256, 0, stream>>>(qkv, vT, fc, fs);
  attn_kernel<<<dim3(32, 16), 512, 0, stream>>>(qkv, vT, (unsigned short*)ob);
  gemm2p<<<256, 512, 0, stream>>>(ob, wo, (float*)d_out, 2048, 4096, 4096, 32);
}

// Round 16
// 308.004 us; speedup vs baseline: 1.0774x; 1.0774x over previous
//
#include <hip/hip_runtime.h>
#include <hip/hip_bf16.h>
#include <stdint.h>

typedef __bf16 bf16_t;
typedef __attribute__((ext_vector_type(8))) __bf16 bf16x8;
typedef __attribute__((ext_vector_type(4))) float f32x4;
typedef __attribute__((ext_vector_type(8))) unsigned short u16x8;

#define S_LEN 2048
#define DIM   4096
#define QKVN  6144
#define NHEAD 32
#define HDIM  128

typedef __attribute__((address_space(1))) unsigned int as1_u32;
typedef __attribute__((address_space(3))) unsigned int as3_u32;

__device__ __forceinline__ unsigned short f2bf(float f) {
  unsigned u = __builtin_bit_cast(unsigned, f);
  u += 0x7fffu + ((u >> 16) & 1u);
  return (unsigned short)(u >> 16);
}

__device__ __forceinline__ void gload_lds16(const void* g, void* l) {
  __builtin_amdgcn_global_load_lds(
      (as1_u32*)(unsigned long long)(uintptr_t)g,
      (as3_u32*)(unsigned int)(uintptr_t)l,
      16, 0, 0);
}

// Fused f32->bf16 conversion for all 5 inputs (one launch, grid-stride).
// Weight conversion amortizes over 8 M-tile re-reads (R15 lesson: direct
// f32 weight reads in-GEMM doubled FETCH to 401MB and regressed).
__global__ __launch_bounds__(256) void cvt5_kernel(const float* __restrict__ x,
                                                   const float* __restrict__ wq,
                                                   const float* __restrict__ wk,
                                                   const float* __restrict__ wv,
                                                   const float* __restrict__ wo,
                                                   ushort4* __restrict__ xb,
                                                   ushort4* __restrict__ wqkvb,
                                                   ushort4* __restrict__ wob) {
  const long N0 = 2097152;           // x  : 2048*4096/4
  const long N1 = N0 + 4194304;      // wq : 4096*4096/4
  const long N2 = N1 + 1048576;      // wk
  const long N3 = N2 + 1048576;      // wv
  const long N4 = N3 + 4194304;      // wo
  long idx = (long)blockIdx.x * 256 + threadIdx.x;
  long stride = (long)gridDim.x * 256;
  for (long i = idx; i < N4; i += stride) {
    const float4* s; ushort4* d; long o;
    if (i < N0)      { s = (const float4*)x;  d = xb;              o = i; }
    else if (i < N1) { s = (const float4*)wq; d = wqkvb;           o = i - N0; }
    else if (i < N2) { s = (const float4*)wk; d = wqkvb + 4194304; o = i - N1; }
    else if (i < N3) { s = (const float4*)wv; d = wqkvb + 5242880; o = i - N2; }
    else             { s = (const float4*)wo; d = wob;             o = i - N3; }
    float4 v = s[o];
    ushort4 r;
    r.x = f2bf(v.x); r.y = f2bf(v.y); r.z = f2bf(v.z); r.w = f2bf(v.w);
    d[o] = r;
  }
}

// Shared swizzled LDS fragment read: chunk ^= (row&7), both sides.
__device__ __forceinline__ bf16x8 fld(const char* half, int row, int chunk) {
  return *(const bf16x8*)(half + row * 128 + ((chunk ^ (row & 7)) << 4));
}

// ---- 256x192 4-phase GEMM, BK=64, 8 waves (2M x 4N) (R11-exact: 109us) --
__global__ __launch_bounds__(512, 2) void gemm8q(const bf16_t* __restrict__ A,
                                                 const bf16_t* __restrict__ B,
                                                 unsigned short* __restrict__ C,
                                                 int M, int N, int K, int nxt) {
  __shared__ char lds[114688];
  const int tid = threadIdx.x;
  const int lane = tid & 63, w = tid >> 6;
  const int wm = w >> 2, wn = w & 3;       // 2 M-waves x 4 N-waves
  const int lg = lane >> 4, lr = lane & 15;
  const int nwg = gridDim.x;
  const int orig = blockIdx.x;
  const int wgid = (orig & 7) * (nwg >> 3) + (orig >> 3);  // nwg % 8 == 0
  const int bx = wgid % nxt, by = wgid / nxt;
  const long rowA = (long)by * 256;
  const long rowB = (long)bx * 192;

  f32x4 acc[8][3];
  const f32x4 z4 = {0.f, 0.f, 0.f, 0.f};
#pragma unroll
  for (int i = 0; i < 8; ++i)
#pragma unroll
    for (int j = 0; j < 3; ++j) acc[i][j] = z4;

  const int r0 = tid >> 3, sl = tid & 7;
  const long xo  = (long)((sl ^ (r0 & 7)) << 3);
  const long aof = (rowA + r0) * (long)K + xo;
  const long bof = (rowB + r0) * (long)K + xo;
  const long j1  = (long)64 * K;
  const long h1  = (long)128 * K;
  const int ld0 = tid * 16, ld1 = (tid + 512) * 16, ld2 = (tid + 1024) * 16;

#define QSTG_A(K0, HALF, DBUF)                                                 \
  { char* hp = lds + (DBUF) * 57344 + (HALF) * 16384;                          \
    gload_lds16(A + aof + (HALF) * h1 + (K0),      hp + ld0);                  \
    gload_lds16(A + aof + (HALF) * h1 + j1 + (K0), hp + ld1); }
#define QSTG_B(K0, DBUF)                                                       \
  { char* bp = lds + (DBUF) * 57344 + 32768;                                   \
    gload_lds16(B + bof + (K0),          bp + ld0);                            \
    gload_lds16(B + bof + j1 + (K0),     bp + ld1);                            \
    gload_lds16(B + bof + 2 * j1 + (K0), bp + ld2); }

  const int nt = K >> 6;
  const int brow = wn * 48;

  QSTG_A(0, 0, 0); QSTG_A(0, 1, 0); QSTG_B(0, 0);
  QSTG_B(64, 1);
  asm volatile("s_waitcnt vmcnt(3)" ::: "memory");
  __builtin_amdgcn_s_barrier();

  bf16x8 af[8][2], bf_[3][2];

  for (int t = 0; t < nt; ++t) {
    const int d = t & 1;
    const char* Ah = lds + d * 57344 + wm * 16384;
    const char* Br = lds + d * 57344 + 32768;
    const int k1 = (t + 1) << 6, k2 = (t + 2) << 6;
    // ---- P0: read A m0-1 + B all; stage A.h0(t+1) ----
#pragma unroll
    for (int m = 0; m < 2; ++m) {
      af[m][0] = fld(Ah, m * 16 + lr, lg);
      af[m][1] = fld(Ah, m * 16 + lr, 4 + lg);
    }
#pragma unroll
    for (int n = 0; n < 3; ++n) {
      bf_[n][0] = fld(Br, brow + n * 16 + lr, lg);
      bf_[n][1] = fld(Br, brow + n * 16 + lr, 4 + lg);
    }
    if (t + 1 < nt) QSTG_A(k1, 0, d ^ 1);
    __builtin_amdgcn_s_barrier();
    asm volatile("s_waitcnt lgkmcnt(0)" ::: "memory");
    __builtin_amdgcn_sched_barrier(0);
    __builtin_amdgcn_s_setprio(1);
#pragma unroll
    for (int m = 0; m < 2; ++m)
#pragma unroll
      for (int n = 0; n < 3; ++n) {
        acc[m][n] = __builtin_amdgcn_mfma_f32_16x16x32_bf16(af[m][0], bf_[n][0], acc[m][n], 0, 0, 0);
        acc[m][n] = __builtin_amdgcn_mfma_f32_16x16x32_bf16(af[m][1], bf_[n][1], acc[m][n], 0, 0, 0);
      }
    __builtin_amdgcn_s_setprio(0);
    __builtin_amdgcn_s_barrier();
    // ---- P1: read A m2-3; stage A.h1(t+1) ----
#pragma unroll
    for (int m = 2; m < 4; ++m) {
      af[m][0] = fld(Ah, m * 16 + lr, lg);
      af[m][1] = fld(Ah, m * 16 + lr, 4 + lg);
    }
    if (t + 1 < nt) QSTG_A(k1, 1, d ^ 1);
    __builtin_amdgcn_s_barrier();
    asm volatile("s_waitcnt lgkmcnt(0)" ::: "memory");
    __builtin_amdgcn_sched_barrier(0);
    __builtin_amdgcn_s_setprio(1);
#pragma unroll
    for (int m = 2; m < 4; ++m)
#pragma unroll
      for (int n = 0; n < 3; ++n) {
        acc[m][n] = __builtin_amdgcn_mfma_f32_16x16x32_bf16(af[m][0], bf_[n][0], acc[m][n], 0, 0, 0);
        acc[m][n] = __builtin_amdgcn_mfma_f32_16x16x32_bf16(af[m][1], bf_[n][1], acc[m][n], 0, 0, 0);
      }
    __builtin_amdgcn_s_setprio(0);
    __builtin_amdgcn_s_barrier();
    // ---- P2: read A m4-5; stage B(t+2) ----
#pragma unroll
    for (int m = 4; m < 6; ++m) {
      af[m][0] = fld(Ah, m * 16 + lr, lg);
      af[m][1] = fld(Ah, m * 16 + lr, 4 + lg);
    }
    if (t + 2 < nt) QSTG_B(k2, d);
    __builtin_amdgcn_s_barrier();
    asm volatile("s_waitcnt lgkmcnt(0)" ::: "memory");
    __builtin_amdgcn_sched_barrier(0);
    __builtin_amdgcn_s_setprio(1);
#pragma unroll
    for (int m = 4; m < 6; ++m)
#pragma unroll
      for (int n = 0; n < 3; ++n) {
        acc[m][n] = __builtin_amdgcn_mfma_f32_16x16x32_bf16(af[m][0], bf_[n][0], acc[m][n], 0, 0, 0);
        acc[m][n] = __builtin_amdgcn_mfma_f32_16x16x32_bf16(af[m][1], bf_[n][1], acc[m][n], 0, 0, 0);
      }
    __builtin_amdgcn_s_setprio(0);
    __builtin_amdgcn_s_barrier();
    // ---- P3: read A m6-7; MFMA; vmcnt(3) ----
#pragma unroll
    for (int m = 6; m < 8; ++m) {
      af[m][0] = fld(Ah, m * 16 + lr, lg);
      af[m][1] = fld(Ah, m * 16 + lr, 4 + lg);
    }
    __builtin_amdgcn_s_barrier();
    asm volatile("s_waitcnt lgkmcnt(0)" ::: "memory");
    __builtin_amdgcn_sched_barrier(0);
    __builtin_amdgcn_s_setprio(1);
#pragma unroll
    for (int m = 6; m < 8; ++m)
#pragma unroll
      for (int n = 0; n < 3; ++n) {
        acc[m][n] = __builtin_amdgcn_mfma_f32_16x16x32_bf16(af[m][0], bf_[n][0], acc[m][n], 0, 0, 0);
        acc[m][n] = __builtin_amdgcn_mfma_f32_16x16x32_bf16(af[m][1], bf_[n][1], acc[m][n], 0, 0, 0);
      }
    __builtin_amdgcn_s_setprio(0);
    if (t + 2 < nt) {
      asm volatile("s_waitcnt vmcnt(3)" ::: "memory");
    } else {
      asm volatile("s_waitcnt vmcnt(0)" ::: "memory");
    }
    __builtin_amdgcn_s_barrier();
  }
#undef QSTG_A
#undef QSTG_B

  const long crow = rowA + wm * 128;
  const long ccol = rowB + wn * 48;
#pragma unroll
  for (int mf = 0; mf < 8; ++mf)
#pragma unroll
    for (int j = 0; j < 4; ++j) {
      long row = crow + mf * 16 + lg * 4 + j;
      unsigned short* cp = C + row * N + ccol + lr;
#pragma unroll
      for (int nf = 0; nf < 3; ++nf) cp[nf * 16] = f2bf(acc[mf][nf][j]);
    }
}

// ---- 256x128 2-phase GEMM, BK=64, 8 waves (R12-verified for O-proj) -----
__global__ __launch_bounds__(512, 2) void gemm2p(const bf16_t* __restrict__ A,
                                                 const bf16_t* __restrict__ B,
                                                 float* __restrict__ C,
                                                 int M, int N, int K, int nxt) {
  __shared__ char lds[147456];
  const int tid = threadIdx.x;
  const int lane = tid & 63, w = tid >> 6;
  const int wm = w >> 1, wn = w & 1;       // 4 M-waves x 2 N-waves, 64x64
  const int lg = lane >> 4, lr = lane & 15;
  const int nwg = gridDim.x;
  const int orig = blockIdx.x;
  const int wgid = (orig & 7) * (nwg >> 3) + (orig >> 3);  // nwg % 8 == 0
  const int bx = wgid % nxt, by = wgid / nxt;
  const long rowA = (long)by * 256;
  const long rowB = (long)bx * 128;

  f32x4 acc[4][4];
  const f32x4 z4 = {0.f, 0.f, 0.f, 0.f};
#pragma unroll
  for (int i = 0; i < 4; ++i)
#pragma unroll
    for (int j = 0; j < 4; ++j) acc[i][j] = z4;

  const int r0 = tid >> 3, sl = tid & 7;
  const long xo  = (long)((sl ^ (r0 & 7)) << 3);
  const long aof = (rowA + r0) * (long)K + xo;
  const long bof = (rowB + r0) * (long)K + xo;
  const long r64 = (long)64 * K;

#define PSTG_A(K0, BUF)                                                        \
  { char* ap = lds + (BUF) * 32768;                                            \
    gload_lds16(A + aof + (K0),           ap + tid * 16);                      \
    gload_lds16(A + aof + r64 + (K0),     ap + (tid + 512) * 16);              \
    gload_lds16(A + aof + 2 * r64 + (K0), ap + (tid + 1024) * 16);             \
    gload_lds16(A + aof + 3 * r64 + (K0), ap + (tid + 1536) * 16); }
#define PSTG_B(K0, BUF)                                                        \
  { char* bp = lds + 98304 + (BUF) * 16384;                                    \
    gload_lds16(B + bof + (K0),       bp + tid * 16);                          \
    gload_lds16(B + bof + r64 + (K0), bp + (tid + 512) * 16); }

  const int nt = K >> 6;

  PSTG_A(0, 0); PSTG_B(0, 0); PSTG_A(64, 1); PSTG_B(64, 1);
  asm volatile("s_waitcnt vmcnt(6)" ::: "memory");
  __builtin_amdgcn_s_barrier();

  bf16x8 af[4][2], bf_[4][2];

  for (int t = 0; t < nt; ++t) {
    const int b3 = t % 3, s3 = (t + 2) % 3;
    const char* Ab = lds + b3 * 32768;
    const char* Bb = lds + 98304 + b3 * 16384;
    const int arow = wm * 64, brow = wn * 64;
    const int k2 = (t + 2) << 6;
#pragma unroll
    for (int m = 0; m < 4; ++m) {
      af[m][0] = fld(Ab, arow + m * 16 + lr, lg);
      af[m][1] = fld(Ab, arow + m * 16 + lr, 4 + lg);
    }
#pragma unroll
    for (int n = 0; n < 2; ++n) {
      bf_[n][0] = fld(Bb, brow + n * 16 + lr, lg);
      bf_[n][1] = fld(Bb, brow + n * 16 + lr, 4 + lg);
    }
    if (t + 2 < nt) PSTG_A(k2, s3);
    __builtin_amdgcn_s_barrier();
    asm volatile("s_waitcnt lgkmcnt(0)" ::: "memory");
    __builtin_amdgcn_sched_barrier(0);
    __builtin_amdgcn_s_setprio(1);
#pragma unroll
    for (int m = 0; m < 4; ++m)
#pragma unroll
      for (int n = 0; n < 2; ++n) {
        acc[m][n] = __builtin_amdgcn_mfma_f32_16x16x32_bf16(af[m][0], bf_[n][0], acc[m][n], 0, 0, 0);
        acc[m][n] = __builtin_amdgcn_mfma_f32_16x16x32_bf16(af[m][1], bf_[n][1], acc[m][n], 0, 0, 0);
      }
    __builtin_amdgcn_s_setprio(0);
    __builtin_amdgcn_s_barrier();
#pragma unroll
    for (int n = 2; n < 4; ++n) {
      bf_[n][0] = fld(Bb, brow + n * 16 + lr, lg);
      bf_[n][1] = fld(Bb, brow + n * 16 + lr, 4 + lg);
    }
    if (t + 2 < nt) PSTG_B(k2, s3);
    __builtin_amdgcn_s_barrier();
    asm volatile("s_waitcnt lgkmcnt(0)" ::: "memory");
    __builtin_amdgcn_sched_barrier(0);
    __builtin_amdgcn_s_setprio(1);
#pragma unroll
    for (int m = 0; m < 4; ++m)
#pragma unroll
      for (int n = 2; n < 4; ++n) {
        acc[m][n] = __builtin_amdgcn_mfma_f32_16x16x32_bf16(af[m][0], bf_[n][0], acc[m][n], 0, 0, 0);
        acc[m][n] = __builtin_amdgcn_mfma_f32_16x16x32_bf16(af[m][1], bf_[n][1], acc[m][n], 0, 0, 0);
      }
    __builtin_amdgcn_s_setprio(0);
    if (t + 2 < nt) {
      asm volatile("s_waitcnt vmcnt(6)" ::: "memory");
    } else {
      asm volatile("s_waitcnt vmcnt(0)" ::: "memory");
    }
    __builtin_amdgcn_s_barrier();
  }
#undef PSTG_A
#undef PSTG_B

  const long crow = rowA + wm * 64;
  const long ccol = rowB + wn * 64;
#pragma unroll
  for (int mf = 0; mf < 4; ++mf)
#pragma unroll
    for (int j = 0; j < 4; ++j) {
      long row = crow + mf * 16 + lg * 4 + j;
      float* cp = C + row * N + ccol + lr;
#pragma unroll
      for (int nf = 0; nf < 4; ++nf) cp[nf * 16] = acc[mf][nf][j];
    }
}

// Merged prep: blocks [0,1024) = V transpose; blocks [1024, 21504) = RoPE.
__global__ __launch_bounds__(256) void prep_kernel(bf16_t* __restrict__ qkv,
                                                   bf16_t* __restrict__ vT,
                                                   const float* __restrict__ cosb,
                                                   const float* __restrict__ sinb) {
  const int bid = blockIdx.x;
  if (bid < 1024) {
    const int kh = bid & 7;
    const int hd = threadIdx.x & 127;
    const int s0 = (bid >> 3) * 16 + (threadIdx.x >> 7) * 8;
    u16x8 v;
#pragma unroll
    for (int e = 0; e < 8; ++e)
      v[e] = *(const unsigned short*)(qkv + (long)(s0 + e) * QKVN + 5120 + kh * HDIM + hd);
    *(u16x8*)(vT + ((long)kh * HDIM + hd) * S_LEN + s0) = v;
  } else {
    int t = (bid - 1024) * 256 + threadIdx.x;
    int i  = t & 63;
    int sh = t >> 6;
    int hh = sh % 40;
    int s  = sh / 40;
    int col2 = (hh < 32) ? (hh * 64 + i) : (2048 + (hh - 32) * 64 + i);
    unsigned int* p = (unsigned int*)qkv + (long)s * (QKVN / 2) + col2;
    unsigned int v = *p;
    float tr = __builtin_bit_cast(float, (v & 0xffffu) << 16);
    float ti = __builtin_bit_cast(float, v & 0xffff0000u);
    float c  = cosb[s * 64 + i];
    float sn = sinb[s * 64 + i];
    float orr = tr * c - ti * sn;
    float oi  = tr * sn + ti * c;
    *p = (unsigned int)f2bf(orr) | ((unsigned int)f2bf(oi) << 16);
  }
}

// Flash attention (R14 + XCD kh-affinity remap): 1-D grid of 512 blocks.
// b -> xcd=b&7, idx=b>>3, head=xcd*4+(idx&3), qi=15-(idx>>2).
// All 4 heads sharing a kv-head land on ONE XCD, adjacent in dispatch at
// the same qi -> K/V tiles hit that XCD's L2 instead of 4x HBM fetches.
__global__ __launch_bounds__(512) void attn_kernel(const bf16_t* __restrict__ qkv,
                                                   const bf16_t* __restrict__ vT,
                                                   unsigned short* __restrict__ ob) {
  __shared__ bf16_t Kt[2][64 * 128];
  __shared__ bf16_t Vt[2][128 * 64];
  __shared__ bf16_t Pl[8 * 16 * 64];
  const int b   = blockIdx.x;
  const int xcd = b & 7, bidx = b >> 3;
  const int h   = xcd * 4 + (bidx & 3);
  const int qi  = 15 - (bidx >> 2);
  const int qb  = qi * 128;
  const int kh  = h >> 2;
  const int tid = threadIdx.x, lane = tid & 63, w = tid >> 6;
  const int lg = lane >> 4, lr = lane & 15;
  const int qrow0 = qb + w * 16;

  bf16x8 qf[4];
  const bf16_t* qptr = qkv + (long)(qrow0 + lr) * QKVN + h * HDIM + lg * 8;
#pragma unroll
  for (int kk = 0; kk < 4; ++kk) qf[kk] = *(const bf16x8*)(qptr + kk * 32);

  const f32x4 z4 = {0.f, 0.f, 0.f, 0.f};
  f32x4 oacc[8];
#pragma unroll
  for (int c = 0; c < 8; ++c) oacc[c] = z4;
  float m[4]     = {-1e30f, -1e30f, -1e30f, -1e30f};
  float plsum[4] = {0.f, 0.f, 0.f, 0.f};

  char* PlB = (char*)Pl + w * 2048;
  const float SCL2 = 0.08838834764831845f * 1.44269504088896f;
  const int ntiles = 2 * qi + 2;
  const int wqmax = qrow0 + 15;

#define STAGE_KV(T, BUF)                                                       \
  {                                                                            \
    const int kvs = (T) * 64;                                                  \
    _Pragma("unroll")                                                          \
    for (int it = 0; it < 2; ++it) {                                           \
      int cch = tid + it * 512;                                                \
      int r = cch >> 4, c = cch & 15;                                          \
      gload_lds16(qkv + (long)(kvs + r) * QKVN + 4096 + kh * HDIM              \
                      + ((c ^ (r & 7)) * 8),                                   \
                  (char*)Kt[BUF] + cch * 16);                                  \
    }                                                                          \
    _Pragma("unroll")                                                          \
    for (int it = 0; it < 2; ++it) {                                           \
      int cch = tid + it * 512;                                                \
      int hd2 = cch >> 3, c = cch & 7;                                         \
      gload_lds16(vT + ((long)kh * HDIM + hd2) * S_LEN + kvs                   \
                      + ((c ^ (hd2 & 7)) * 8),                                 \
                  (char*)Vt[BUF] + cch * 16);                                  \
    }                                                                          \
  }

  STAGE_KV(0, 0);
  STAGE_KV(1, 1);
  asm volatile("s_waitcnt vmcnt(4)" ::: "memory");
  __builtin_amdgcn_s_barrier();

  for (int t = 0; t < ntiles; ++t) {
    const int kv0 = t * 64;
    const int d = t & 1;
    if (kv0 <= wqmax) {
      char* KtB = (char*)Kt[d];
      char* VtB = (char*)Vt[d];

      f32x4 sf[4];
#pragma unroll
      for (int f = 0; f < 4; ++f) {
        f32x4 a = z4;
        int n = f * 16 + lr;
        int rb = n * 256, sw = (n & 7) << 4;
#pragma unroll
        for (int kk = 0; kk < 4; ++kk) {
          bf16x8 kf = *(const bf16x8*)(KtB + rb + (((kk * 4 + lg) * 16) ^ sw));
          a = __builtin_amdgcn_mfma_f32_16x16x32_bf16(qf[kk], kf, a, 0, 0, 0);
        }
        sf[f] = a;
      }

      float sv[4][4], lmax[4];
      if (kv0 + 63 <= qrow0) {
#pragma unroll
        for (int j = 0; j < 4; ++j) {
#pragma unroll
          for (int f = 0; f < 4; ++f) sv[j][f] = sf[f][j] * SCL2;
          lmax[j] = fmaxf(fmaxf(sv[j][0], sv[j][1]), fmaxf(sv[j][2], sv[j][3]));
        }
      } else {
#pragma unroll
        for (int j = 0; j < 4; ++j) {
          int qrow = qrow0 + lg * 4 + j;
#pragma unroll
          for (int f = 0; f < 4; ++f) {
            float s = sf[f][j] * SCL2;
            if (kv0 + f * 16 + lr > qrow) s = -1e9f;
            sv[j][f] = s;
          }
          lmax[j] = fmaxf(fmaxf(sv[j][0], sv[j][1]), fmaxf(sv[j][2], sv[j][3]));
        }
      }
      float g = fmaxf(fmaxf(lmax[0] - m[0], lmax[1] - m[1]),
                      fmaxf(lmax[2] - m[2], lmax[3] - m[3]));
      if (__any(g > 0.f)) {
#pragma unroll
        for (int j = 0; j < 4; ++j) {
          float t0 = lmax[j];
          t0 = fmaxf(t0, __shfl_xor(t0, 1));
          t0 = fmaxf(t0, __shfl_xor(t0, 2));
          t0 = fmaxf(t0, __shfl_xor(t0, 4));
          t0 = fmaxf(t0, __shfl_xor(t0, 8));
          float mn = fmaxf(m[j], t0);
          float sc;
          asm("v_exp_f32 %0, %1" : "=v"(sc) : "v"(m[j] - mn));
          plsum[j] *= sc;
          m[j] = mn;
#pragma unroll
          for (int c = 0; c < 8; ++c) oacc[c][j] *= sc;
        }
      }
#pragma unroll
      for (int j = 0; j < 4; ++j) {
        float p[4];
#pragma unroll
        for (int f = 0; f < 4; ++f)
          asm("v_exp_f32 %0, %1" : "=v"(p[f]) : "v"(sv[j][f] - m[j]));
        plsum[j] += (p[0] + p[1]) + (p[2] + p[3]);
        int row = lg * 4 + j;
        int swp = (row & 7) << 4;
#pragma unroll
        for (int f = 0; f < 4; ++f)
          *(unsigned short*)(PlB + row * 128 + (((f * 16 + lr) * 2) ^ swp)) = f2bf(p[f]);
      }

      bf16x8 pfr[2];
#pragma unroll
      for (int kk = 0; kk < 2; ++kk)
        pfr[kk] = *(const bf16x8*)(PlB + lr * 128 + (((kk * 4 + lg) * 16) ^ ((lr & 7) << 4)));
#pragma unroll
      for (int c = 0; c < 8; ++c) {
        int hd = c * 16 + lr;
        int rb = hd * 128, sw = (hd & 7) << 4;
#pragma unroll
        for (int kk = 0; kk < 2; ++kk) {
          bf16x8 vf = *(const bf16x8*)(VtB + rb + (((kk * 4 + lg) * 16) ^ sw));
          oacc[c] = __builtin_amdgcn_mfma_f32_16x16x32_bf16(pfr[kk], vf, oacc[c], 0, 0, 0);
        }
      }
    }
    __builtin_amdgcn_s_barrier();
    if (t + 2 < ntiles) {
      STAGE_KV(t + 2, d);
      asm volatile("s_waitcnt vmcnt(4)" ::: "memory");
    } else {
      asm volatile("s_waitcnt vmcnt(0)" ::: "memory");
    }
    __builtin_amdgcn_s_barrier();
  }
#undef STAGE_KV

  float rl[4];
#pragma unroll
  for (int j = 0; j < 4; ++j) {
    float s = plsum[j];
    s += __shfl_xor(s, 1);
    s += __shfl_xor(s, 2);
    s += __shfl_xor(s, 4);
    s += __shfl_xor(s, 8);
    rl[j] = 1.f / s;
  }
#pragma unroll
  for (int c = 0; c < 8; ++c)
#pragma unroll
    for (int j = 0; j < 4; ++j) {
      long row = qrow0 + lg * 4 + j;
      ob[row * 4096 + h * 128 + c * 16 + lr] = f2bf(oacc[c][j] * rl[j]);
    }
}

extern "C" void kernel_launch(void* const* d_in, const int* in_sizes, int n_in,
                              void* d_out, int out_size, void* d_ws, size_t ws_size,
                              hipStream_t stream) {
  const float* x  = (const float*)d_in[0];
  const float* wq = (const float*)d_in[1];
  const float* wk = (const float*)d_in[2];
  const float* wv = (const float*)d_in[3];
  const float* wo = (const float*)d_in[4];
  const float* fc = (const float*)d_in[5];
  const float* fs = (const float*)d_in[6];

  char* ws = (char*)d_ws;
  bf16_t* xb    = (bf16_t*)(ws + 0);          // 2048x4096 (dead after gemm1)
  bf16_t* wqkvb = (bf16_t*)(ws + 16777216);   // 6144x4096
  bf16_t* wob   = (bf16_t*)(ws + 67108864);   // 4096x4096
  bf16_t* qkv   = (bf16_t*)(ws + 100663296);  // 2048x6144
  bf16_t* ob    = (bf16_t*)(ws + 125829120);  // 2048x4096
  bf16_t* vT    = (bf16_t*)(ws + 0);          // 8x128x2048 (4 MB, reuses xb)

  cvt5_kernel<<<2048, 256, 0, stream>>>(x, wq, wk, wv, wo,
                                        (ushort4*)xb, (ushort4*)wqkvb, (ushort4*)wob);

  gemm8q<<<256, 512, 0, stream>>>(xb, wqkvb, (unsigned short*)qkv,
                                  2048, 6144, 4096, 32);
  prep_kernel<<<21504, 256, 0, stream>>>(qkv, vT, fc, fs);
  attn_kernel<<<512, 512, 0, stream>>>(qkv, vT, (unsigned short*)ob);
  gemm2p<<<256, 512, 0, stream>>>(ob, wob, (float*)d_out, 2048, 4096, 4096, 32);
}

// Round 17
// 305.497 us; speedup vs baseline: 1.0863x; 1.0082x over previous
//
#include <hip/hip_runtime.h>
#include <hip/hip_bf16.h>
#include <stdint.h>

typedef __bf16 bf16_t;
typedef __attribute__((ext_vector_type(8))) __bf16 bf16x8;
typedef __attribute__((ext_vector_type(4))) float f32x4;
typedef __attribute__((ext_vector_type(8))) unsigned short u16x8;

#define S_LEN 2048
#define DIM   4096
#define QKVN  6144
#define NHEAD 32
#define HDIM  128

typedef __attribute__((address_space(1))) unsigned int as1_u32;
typedef __attribute__((address_space(3))) unsigned int as3_u32;

__device__ __forceinline__ unsigned short f2bf(float f) {
  unsigned u = __builtin_bit_cast(unsigned, f);
  u += 0x7fffu + ((u >> 16) & 1u);
  return (unsigned short)(u >> 16);
}

__device__ __forceinline__ void gload_lds16(const void* g, void* l) {
  __builtin_amdgcn_global_load_lds(
      (as1_u32*)(unsigned long long)(uintptr_t)g,
      (as3_u32*)(unsigned int)(uintptr_t)l,
      16, 0, 0);
}

// Fused f32->bf16 conversion for all 5 inputs (one launch, grid-stride).
// At its HBM floor (432 MB ~ 69us). R15 lesson: in-GEMM f32 reads regress.
__global__ __launch_bounds__(256) void cvt5_kernel(const float* __restrict__ x,
                                                   const float* __restrict__ wq,
                                                   const float* __restrict__ wk,
                                                   const float* __restrict__ wv,
                                                   const float* __restrict__ wo,
                                                   ushort4* __restrict__ xb,
                                                   ushort4* __restrict__ wqkvb,
                                                   ushort4* __restrict__ wob) {
  const long N0 = 2097152;           // x  : 2048*4096/4
  const long N1 = N0 + 4194304;      // wq : 4096*4096/4
  const long N2 = N1 + 1048576;      // wk
  const long N3 = N2 + 1048576;      // wv
  const long N4 = N3 + 4194304;      // wo
  long idx = (long)blockIdx.x * 256 + threadIdx.x;
  long stride = (long)gridDim.x * 256;
  for (long i = idx; i < N4; i += stride) {
    const float4* s; ushort4* d; long o;
    if (i < N0)      { s = (const float4*)x;  d = xb;              o = i; }
    else if (i < N1) { s = (const float4*)wq; d = wqkvb;           o = i - N0; }
    else if (i < N2) { s = (const float4*)wk; d = wqkvb + 4194304; o = i - N1; }
    else if (i < N3) { s = (const float4*)wv; d = wqkvb + 5242880; o = i - N2; }
    else             { s = (const float4*)wo; d = wob;             o = i - N3; }
    float4 v = s[o];
    ushort4 r;
    r.x = f2bf(v.x); r.y = f2bf(v.y); r.z = f2bf(v.z); r.w = f2bf(v.w);
    d[o] = r;
  }
}

// Shared swizzled LDS fragment read: chunk ^= (row&7), both sides.
__device__ __forceinline__ bf16x8 fld(const char* half, int row, int chunk) {
  return *(const bf16x8*)(half + row * 128 + ((chunk ^ (row & 7)) << 4));
}

// ---- 256x192 2-PHASE GEMM, BK=64, 8 waves (2M x 4N), 24 MFMA/phase ------
// A triple-buffered (3x32K), B double-buffered (2x24K) = 144KB LDS.
// P0: ds_read {B all(6) + A m0-3(8)}; stage A(t+2)->buf (t+2)%3; lgkm(0);
//     24 MFMA (m0-3 x n0-2 x 2ks).
// P1: ds_read {A m4-7(8)}; stage B(t+2)->dbuf t&1 [B(t) consumed at P0];
//     lgkm(0); 24 MFMA; vmcnt(7) [drains A(t+1)+B(t+1); t+2's 7 in flight].
__global__ __launch_bounds__(512, 2) void gemm8q(const bf16_t* __restrict__ A,
                                                 const bf16_t* __restrict__ B,
                                                 unsigned short* __restrict__ C,
                                                 int M, int N, int K, int nxt) {
  __shared__ char lds[147456];   // A 3x32K @0; B 2x24K @98304
  const int tid = threadIdx.x;
  const int lane = tid & 63, w = tid >> 6;
  const int wm = w >> 2, wn = w & 3;       // 2 M-waves x 4 N-waves
  const int lg = lane >> 4, lr = lane & 15;
  const int nwg = gridDim.x;
  const int orig = blockIdx.x;
  const int wgid = (orig & 7) * (nwg >> 3) + (orig >> 3);  // nwg % 8 == 0
  const int bx = wgid % nxt, by = wgid / nxt;
  const long rowA = (long)by * 256;
  const long rowB = (long)bx * 192;

  f32x4 acc[8][3];
  const f32x4 z4 = {0.f, 0.f, 0.f, 0.f};
#pragma unroll
  for (int i = 0; i < 8; ++i)
#pragma unroll
    for (int j = 0; j < 3; ++j) acc[i][j] = z4;

  const int r0 = tid >> 3, sl = tid & 7;
  const long xo  = (long)((sl ^ (r0 & 7)) << 3);
  const long aof = (rowA + r0) * (long)K + xo;
  const long bof = (rowB + r0) * (long)K + xo;
  const long j1  = (long)64 * K;
  const long h1  = (long)128 * K;
  const int ld0 = tid * 16, ld1 = (tid + 512) * 16, ld2 = (tid + 1024) * 16;

#define QSTG_A(K0, BUF3)                                                       \
  { char* hp = lds + (BUF3) * 32768;                                           \
    gload_lds16(A + aof + (K0),           hp + ld0);                           \
    gload_lds16(A + aof + j1 + (K0),      hp + ld1);                           \
    gload_lds16(A + aof + h1 + (K0),      hp + 16384 + ld0);                   \
    gload_lds16(A + aof + h1 + j1 + (K0), hp + 16384 + ld1); }
#define QSTG_B(K0, DBUF)                                                       \
  { char* bp = lds + 98304 + (DBUF) * 24576;                                   \
    gload_lds16(B + bof + (K0),          bp + ld0);                            \
    gload_lds16(B + bof + j1 + (K0),     bp + ld1);                            \
    gload_lds16(B + bof + 2 * j1 + (K0), bp + ld2); }

  const int nt = K >> 6;
  const int brow = wn * 48;

  // prologue: A(0),B(0),A(1),B(1) FIFO; vmcnt(7) -> tile0 landed.
  QSTG_A(0, 0);  QSTG_B(0, 0);
  QSTG_A(64, 1); QSTG_B(64, 1);
  asm volatile("s_waitcnt vmcnt(7)" ::: "memory");
  __builtin_amdgcn_s_barrier();

  bf16x8 af[8][2], bf_[3][2];

  for (int t = 0; t < nt; ++t) {
    const int a3 = t % 3, s3 = (t + 2) % 3, d = t & 1;
    const char* Ah = lds + a3 * 32768 + wm * 16384;
    const char* Br = lds + 98304 + d * 24576;
    const int k2 = (t + 2) << 6;
    // ---- P0: read B all + A m0-3; stage A(t+2) ----
#pragma unroll
    for (int n = 0; n < 3; ++n) {
      bf_[n][0] = fld(Br, brow + n * 16 + lr, lg);
      bf_[n][1] = fld(Br, brow + n * 16 + lr, 4 + lg);
    }
#pragma unroll
    for (int m = 0; m < 4; ++m) {
      af[m][0] = fld(Ah, m * 16 + lr, lg);
      af[m][1] = fld(Ah, m * 16 + lr, 4 + lg);
    }
    if (t + 2 < nt) QSTG_A(k2, s3);
    __builtin_amdgcn_s_barrier();
    asm volatile("s_waitcnt lgkmcnt(0)" ::: "memory");
    __builtin_amdgcn_sched_barrier(0);
    __builtin_amdgcn_s_setprio(1);
#pragma unroll
    for (int m = 0; m < 4; ++m)
#pragma unroll
      for (int n = 0; n < 3; ++n) {
        acc[m][n] = __builtin_amdgcn_mfma_f32_16x16x32_bf16(af[m][0], bf_[n][0], acc[m][n], 0, 0, 0);
        acc[m][n] = __builtin_amdgcn_mfma_f32_16x16x32_bf16(af[m][1], bf_[n][1], acc[m][n], 0, 0, 0);
      }
    __builtin_amdgcn_s_setprio(0);
    __builtin_amdgcn_s_barrier();
    // ---- P1: read A m4-7; stage B(t+2); vmcnt(7) ----
#pragma unroll
    for (int m = 4; m < 8; ++m) {
      af[m][0] = fld(Ah, m * 16 + lr, lg);
      af[m][1] = fld(Ah, m * 16 + lr, 4 + lg);
    }
    if (t + 2 < nt) QSTG_B(k2, d);
    __builtin_amdgcn_s_barrier();
    asm volatile("s_waitcnt lgkmcnt(0)" ::: "memory");
    __builtin_amdgcn_sched_barrier(0);
    __builtin_amdgcn_s_setprio(1);
#pragma unroll
    for (int m = 4; m < 8; ++m)
#pragma unroll
      for (int n = 0; n < 3; ++n) {
        acc[m][n] = __builtin_amdgcn_mfma_f32_16x16x32_bf16(af[m][0], bf_[n][0], acc[m][n], 0, 0, 0);
        acc[m][n] = __builtin_amdgcn_mfma_f32_16x16x32_bf16(af[m][1], bf_[n][1], acc[m][n], 0, 0, 0);
      }
    __builtin_amdgcn_s_setprio(0);
    if (t + 2 < nt) {
      asm volatile("s_waitcnt vmcnt(7)" ::: "memory");
    } else {
      asm volatile("s_waitcnt vmcnt(0)" ::: "memory");
    }
    __builtin_amdgcn_s_barrier();
  }
#undef QSTG_A
#undef QSTG_B

  const long crow = rowA + wm * 128;
  const long ccol = rowB + wn * 48;
#pragma unroll
  for (int mf = 0; mf < 8; ++mf)
#pragma unroll
    for (int j = 0; j < 4; ++j) {
      long row = crow + mf * 16 + lg * 4 + j;
      unsigned short* cp = C + row * N + ccol + lr;
#pragma unroll
      for (int nf = 0; nf < 3; ++nf) cp[nf * 16] = f2bf(acc[mf][nf][j]);
    }
}

// ---- 256x128 2-phase GEMM, BK=64, 8 waves (R12-verified for O-proj) -----
__global__ __launch_bounds__(512, 2) void gemm2p(const bf16_t* __restrict__ A,
                                                 const bf16_t* __restrict__ B,
                                                 float* __restrict__ C,
                                                 int M, int N, int K, int nxt) {
  __shared__ char lds[147456];
  const int tid = threadIdx.x;
  const int lane = tid & 63, w = tid >> 6;
  const int wm = w >> 1, wn = w & 1;       // 4 M-waves x 2 N-waves, 64x64
  const int lg = lane >> 4, lr = lane & 15;
  const int nwg = gridDim.x;
  const int orig = blockIdx.x;
  const int wgid = (orig & 7) * (nwg >> 3) + (orig >> 3);  // nwg % 8 == 0
  const int bx = wgid % nxt, by = wgid / nxt;
  const long rowA = (long)by * 256;
  const long rowB = (long)bx * 128;

  f32x4 acc[4][4];
  const f32x4 z4 = {0.f, 0.f, 0.f, 0.f};
#pragma unroll
  for (int i = 0; i < 4; ++i)
#pragma unroll
    for (int j = 0; j < 4; ++j) acc[i][j] = z4;

  const int r0 = tid >> 3, sl = tid & 7;
  const long xo  = (long)((sl ^ (r0 & 7)) << 3);
  const long aof = (rowA + r0) * (long)K + xo;
  const long bof = (rowB + r0) * (long)K + xo;
  const long r64 = (long)64 * K;

#define PSTG_A(K0, BUF)                                                        \
  { char* ap = lds + (BUF) * 32768;                                            \
    gload_lds16(A + aof + (K0),           ap + tid * 16);                      \
    gload_lds16(A + aof + r64 + (K0),     ap + (tid + 512) * 16);              \
    gload_lds16(A + aof + 2 * r64 + (K0), ap + (tid + 1024) * 16);             \
    gload_lds16(A + aof + 3 * r64 + (K0), ap + (tid + 1536) * 16); }
#define PSTG_B(K0, BUF)                                                        \
  { char* bp = lds + 98304 + (BUF) * 16384;                                    \
    gload_lds16(B + bof + (K0),       bp + tid * 16);                          \
    gload_lds16(B + bof + r64 + (K0), bp + (tid + 512) * 16); }

  const int nt = K >> 6;

  PSTG_A(0, 0); PSTG_B(0, 0); PSTG_A(64, 1); PSTG_B(64, 1);
  asm volatile("s_waitcnt vmcnt(6)" ::: "memory");
  __builtin_amdgcn_s_barrier();

  bf16x8 af[4][2], bf_[4][2];

  for (int t = 0; t < nt; ++t) {
    const int b3 = t % 3, s3 = (t + 2) % 3;
    const char* Ab = lds + b3 * 32768;
    const char* Bb = lds + 98304 + b3 * 16384;
    const int arow = wm * 64, brow = wn * 64;
    const int k2 = (t + 2) << 6;
#pragma unroll
    for (int m = 0; m < 4; ++m) {
      af[m][0] = fld(Ab, arow + m * 16 + lr, lg);
      af[m][1] = fld(Ab, arow + m * 16 + lr, 4 + lg);
    }
#pragma unroll
    for (int n = 0; n < 2; ++n) {
      bf_[n][0] = fld(Bb, brow + n * 16 + lr, lg);
      bf_[n][1] = fld(Bb, brow + n * 16 + lr, 4 + lg);
    }
    if (t + 2 < nt) PSTG_A(k2, s3);
    __builtin_amdgcn_s_barrier();
    asm volatile("s_waitcnt lgkmcnt(0)" ::: "memory");
    __builtin_amdgcn_sched_barrier(0);
    __builtin_amdgcn_s_setprio(1);
#pragma unroll
    for (int m = 0; m < 4; ++m)
#pragma unroll
      for (int n = 0; n < 2; ++n) {
        acc[m][n] = __builtin_amdgcn_mfma_f32_16x16x32_bf16(af[m][0], bf_[n][0], acc[m][n], 0, 0, 0);
        acc[m][n] = __builtin_amdgcn_mfma_f32_16x16x32_bf16(af[m][1], bf_[n][1], acc[m][n], 0, 0, 0);
      }
    __builtin_amdgcn_s_setprio(0);
    __builtin_amdgcn_s_barrier();
#pragma unroll
    for (int n = 2; n < 4; ++n) {
      bf_[n][0] = fld(Bb, brow + n * 16 + lr, lg);
      bf_[n][1] = fld(Bb, brow + n * 16 + lr, 4 + lg);
    }
    if (t + 2 < nt) PSTG_B(k2, s3);
    __builtin_amdgcn_s_barrier();
    asm volatile("s_waitcnt lgkmcnt(0)" ::: "memory");
    __builtin_amdgcn_sched_barrier(0);
    __builtin_amdgcn_s_setprio(1);
#pragma unroll
    for (int m = 0; m < 4; ++m)
#pragma unroll
      for (int n = 2; n < 4; ++n) {
        acc[m][n] = __builtin_amdgcn_mfma_f32_16x16x32_bf16(af[m][0], bf_[n][0], acc[m][n], 0, 0, 0);
        acc[m][n] = __builtin_amdgcn_mfma_f32_16x16x32_bf16(af[m][1], bf_[n][1], acc[m][n], 0, 0, 0);
      }
    __builtin_amdgcn_s_setprio(0);
    if (t + 2 < nt) {
      asm volatile("s_waitcnt vmcnt(6)" ::: "memory");
    } else {
      asm volatile("s_waitcnt vmcnt(0)" ::: "memory");
    }
    __builtin_amdgcn_s_barrier();
  }
#undef PSTG_A
#undef PSTG_B

  const long crow = rowA + wm * 64;
  const long ccol = rowB + wn * 64;
#pragma unroll
  for (int mf = 0; mf < 4; ++mf)
#pragma unroll
    for (int j = 0; j < 4; ++j) {
      long row = crow + mf * 16 + lg * 4 + j;
      float* cp = C + row * N + ccol + lr;
#pragma unroll
      for (int nf = 0; nf < 4; ++nf) cp[nf * 16] = acc[mf][nf][j];
    }
}

// Merged prep: blocks [0,1024) = V transpose; blocks [1024, 21504) = RoPE.
__global__ __launch_bounds__(256) void prep_kernel(bf16_t* __restrict__ qkv,
                                                   bf16_t* __restrict__ vT,
                                                   const float* __restrict__ cosb,
                                                   const float* __restrict__ sinb) {
  const int bid = blockIdx.x;
  if (bid < 1024) {
    const int kh = bid & 7;
    const int hd = threadIdx.x & 127;
    const int s0 = (bid >> 3) * 16 + (threadIdx.x >> 7) * 8;
    u16x8 v;
#pragma unroll
    for (int e = 0; e < 8; ++e)
      v[e] = *(const unsigned short*)(qkv + (long)(s0 + e) * QKVN + 5120 + kh * HDIM + hd);
    *(u16x8*)(vT + ((long)kh * HDIM + hd) * S_LEN + s0) = v;
  } else {
    int t = (bid - 1024) * 256 + threadIdx.x;
    int i  = t & 63;
    int sh = t >> 6;
    int hh = sh % 40;
    int s  = sh / 40;
    int col2 = (hh < 32) ? (hh * 64 + i) : (2048 + (hh - 32) * 64 + i);
    unsigned int* p = (unsigned int*)qkv + (long)s * (QKVN / 2) + col2;
    unsigned int v = *p;
    float tr = __builtin_bit_cast(float, (v & 0xffffu) << 16);
    float ti = __builtin_bit_cast(float, v & 0xffff0000u);
    float c  = cosb[s * 64 + i];
    float sn = sinb[s * 64 + i];
    float orr = tr * c - ti * sn;
    float oi  = tr * sn + ti * c;
    *p = (unsigned int)f2bf(orr) | ((unsigned int)f2bf(oi) << 16);
  }
}

// Flash attention (R16-verified): XCD kh-affinity remap, K/V dbuf,
// per-lane plsum, __any-gated max reduce.
__global__ __launch_bounds__(512) void attn_kernel(const bf16_t* __restrict__ qkv,
                                                   const bf16_t* __restrict__ vT,
                                                   unsigned short* __restrict__ ob) {
  __shared__ bf16_t Kt[2][64 * 128];
  __shared__ bf16_t Vt[2][128 * 64];
  __shared__ bf16_t Pl[8 * 16 * 64];
  const int b   = blockIdx.x;
  const int xcd = b & 7, bidx = b >> 3;
  const int h   = xcd * 4 + (bidx & 3);
  const int qi  = 15 - (bidx >> 2);
  const int qb  = qi * 128;
  const int kh  = h >> 2;
  const int tid = threadIdx.x, lane = tid & 63, w = tid >> 6;
  const int lg = lane >> 4, lr = lane & 15;
  const int qrow0 = qb + w * 16;

  bf16x8 qf[4];
  const bf16_t* qptr = qkv + (long)(qrow0 + lr) * QKVN + h * HDIM + lg * 8;
#pragma unroll
  for (int kk = 0; kk < 4; ++kk) qf[kk] = *(const bf16x8*)(qptr + kk * 32);

  const f32x4 z4 = {0.f, 0.f, 0.f, 0.f};
  f32x4 oacc[8];
#pragma unroll
  for (int c = 0; c < 8; ++c) oacc[c] = z4;
  float m[4]     = {-1e30f, -1e30f, -1e30f, -1e30f};
  float plsum[4] = {0.f, 0.f, 0.f, 0.f};

  char* PlB = (char*)Pl + w * 2048;
  const float SCL2 = 0.08838834764831845f * 1.44269504088896f;
  const int ntiles = 2 * qi + 2;
  const int wqmax = qrow0 + 15;

#define STAGE_KV(T, BUF)                                                       \
  {                                                                            \
    const int kvs = (T) * 64;                                                  \
    _Pragma("unroll")                                                          \
    for (int it = 0; it < 2; ++it) {                                           \
      int cch = tid + it * 512;                                                \
      int r = cch >> 4, c = cch & 15;                                          \
      gload_lds16(qkv + (long)(kvs + r) * QKVN + 4096 + kh * HDIM              \
                      + ((c ^ (r & 7)) * 8),                                   \
                  (char*)Kt[BUF] + cch * 16);                                  \
    }                                                                          \
    _Pragma("unroll")                                                          \
    for (int it = 0; it < 2; ++it) {                                           \
      int cch = tid + it * 512;                                                \
      int hd2 = cch >> 3, c = cch & 7;                                         \
      gload_lds16(vT + ((long)kh * HDIM + hd2) * S_LEN + kvs                   \
                      + ((c ^ (hd2 & 7)) * 8),                                 \
                  (char*)Vt[BUF] + cch * 16);                                  \
    }                                                                          \
  }

  STAGE_KV(0, 0);
  STAGE_KV(1, 1);
  asm volatile("s_waitcnt vmcnt(4)" ::: "memory");
  __builtin_amdgcn_s_barrier();

  for (int t = 0; t < ntiles; ++t) {
    const int kv0 = t * 64;
    const int d = t & 1;
    if (kv0 <= wqmax) {
      char* KtB = (char*)Kt[d];
      char* VtB = (char*)Vt[d];

      f32x4 sf[4];
#pragma unroll
      for (int f = 0; f < 4; ++f) {
        f32x4 a = z4;
        int n = f * 16 + lr;
        int rb = n * 256, sw = (n & 7) << 4;
#pragma unroll
        for (int kk = 0; kk < 4; ++kk) {
          bf16x8 kf = *(const bf16x8*)(KtB + rb + (((kk * 4 + lg) * 16) ^ sw));
          a = __builtin_amdgcn_mfma_f32_16x16x32_bf16(qf[kk], kf, a, 0, 0, 0);
        }
        sf[f] = a;
      }

      float sv[4][4], lmax[4];
      if (kv0 + 63 <= qrow0) {
#pragma unroll
        for (int j = 0; j < 4; ++j) {
#pragma unroll
          for (int f = 0; f < 4; ++f) sv[j][f] = sf[f][j] * SCL2;
          lmax[j] = fmaxf(fmaxf(sv[j][0], sv[j][1]), fmaxf(sv[j][2], sv[j][3]));
        }
      } else {
#pragma unroll
        for (int j = 0; j < 4; ++j) {
          int qrow = qrow0 + lg * 4 + j;
#pragma unroll
          for (int f = 0; f < 4; ++f) {
            float s = sf[f][j] * SCL2;
            if (kv0 + f * 16 + lr > qrow) s = -1e9f;
            sv[j][f] = s;
          }
          lmax[j] = fmaxf(fmaxf(sv[j][0], sv[j][1]), fmaxf(sv[j][2], sv[j][3]));
        }
      }
      float g = fmaxf(fmaxf(lmax[0] - m[0], lmax[1] - m[1]),
                      fmaxf(lmax[2] - m[2], lmax[3] - m[3]));
      if (__any(g > 0.f)) {
#pragma unroll
        for (int j = 0; j < 4; ++j) {
          float t0 = lmax[j];
          t0 = fmaxf(t0, __shfl_xor(t0, 1));
          t0 = fmaxf(t0, __shfl_xor(t0, 2));
          t0 = fmaxf(t0, __shfl_xor(t0, 4));
          t0 = fmaxf(t0, __shfl_xor(t0, 8));
          float mn = fmaxf(m[j], t0);
          float sc;
          asm("v_exp_f32 %0, %1" : "=v"(sc) : "v"(m[j] - mn));
          plsum[j] *= sc;
          m[j] = mn;
#pragma unroll
          for (int c = 0; c < 8; ++c) oacc[c][j] *= sc;
        }
      }
#pragma unroll
      for (int j = 0; j < 4; ++j) {
        float p[4];
#pragma unroll
        for (int f = 0; f < 4; ++f)
          asm("v_exp_f32 %0, %1" : "=v"(p[f]) : "v"(sv[j][f] - m[j]));
        plsum[j] += (p[0] + p[1]) + (p[2] + p[3]);
        int row = lg * 4 + j;
        int swp = (row & 7) << 4;
#pragma unroll
        for (int f = 0; f < 4; ++f)
          *(unsigned short*)(PlB + row * 128 + (((f * 16 + lr) * 2) ^ swp)) = f2bf(p[f]);
      }

      bf16x8 pfr[2];
#pragma unroll
      for (int kk = 0; kk < 2; ++kk)
        pfr[kk] = *(const bf16x8*)(PlB + lr * 128 + (((kk * 4 + lg) * 16) ^ ((lr & 7) << 4)));
#pragma unroll
      for (int c = 0; c < 8; ++c) {
        int hd = c * 16 + lr;
        int rb = hd * 128, sw = (hd & 7) << 4;
#pragma unroll
        for (int kk = 0; kk < 2; ++kk) {
          bf16x8 vf = *(const bf16x8*)(VtB + rb + (((kk * 4 + lg) * 16) ^ sw));
          oacc[c] = __builtin_amdgcn_mfma_f32_16x16x32_bf16(pfr[kk], vf, oacc[c], 0, 0, 0);
        }
      }
    }
    __builtin_amdgcn_s_barrier();
    if (t + 2 < ntiles) {
      STAGE_KV(t + 2, d);
      asm volatile("s_waitcnt vmcnt(4)" ::: "memory");
    } else {
      asm volatile("s_waitcnt vmcnt(0)" ::: "memory");
    }
    __builtin_amdgcn_s_barrier();
  }
#undef STAGE_KV

  float rl[4];
#pragma unroll
  for (int j = 0; j < 4; ++j) {
    float s = plsum[j];
    s += __shfl_xor(s, 1);
    s += __shfl_xor(s, 2);
    s += __shfl_xor(s, 4);
    s += __shfl_xor(s, 8);
    rl[j] = 1.f / s;
  }
#pragma unroll
  for (int c = 0; c < 8; ++c)
#pragma unroll
    for (int j = 0; j < 4; ++j) {
      long row = qrow0 + lg * 4 + j;
      ob[row * 4096 + h * 128 + c * 16 + lr] = f2bf(oacc[c][j] * rl[j]);
    }
}

extern "C" void kernel_launch(void* const* d_in, const int* in_sizes, int n_in,
                              void* d_out, int out_size, void* d_ws, size_t ws_size,
                              hipStream_t stream) {
  const float* x  = (const float*)d_in[0];
  const float* wq = (const float*)d_in[1];
  const float* wk = (const float*)d_in[2];
  const float* wv = (const float*)d_in[3];
  const float* wo = (const float*)d_in[4];
  const float* fc = (const float*)d_in[5];
  const float* fs = (const float*)d_in[6];

  char* ws = (char*)d_ws;
  bf16_t* xb    = (bf16_t*)(ws + 0);          // 2048x4096 (dead after gemm1)
  bf16_t* wqkvb = (bf16_t*)(ws + 16777216);   // 6144x4096
  bf16_t* wob   = (bf16_t*)(ws + 67108864);   // 4096x4096
  bf16_t* qkv   = (bf16_t*)(ws + 100663296);  // 2048x6144
  bf16_t* ob    = (bf16_t*)(ws + 125829120);  // 2048x4096
  bf16_t* vT    = (bf16_t*)(ws + 0);          // 8x128x2048 (4 MB, reuses xb)

  cvt5_kernel<<<2048, 256, 0, stream>>>(x, wq, wk, wv, wo,
                                        (ushort4*)xb, (ushort4*)wqkvb, (ushort4*)wob);

  gemm8q<<<256, 512, 0, stream>>>(xb, wqkvb, (unsigned short*)qkv,
                                  2048, 6144, 4096, 32);
  prep_kernel<<<21504, 256, 0, stream>>>(qkv, vT, fc, fs);
  attn_kernel<<<512, 512, 0, stream>>>(qkv, vT, (unsigned short*)ob);
  gemm2p<<<256, 512, 0, stream>>>(ob, wob, (float*)d_out, 2048, 4096, 4096, 32);
}

// Round 18
// 299.592 us; speedup vs baseline: 1.1077x; 1.0197x over previous
//
#include <hip/hip_runtime.h>
#include <hip/hip_bf16.h>
#include <stdint.h>

typedef __bf16 bf16_t;
typedef __attribute__((ext_vector_type(8))) __bf16 bf16x8;
typedef __attribute__((ext_vector_type(4))) float f32x4;
typedef __attribute__((ext_vector_type(8))) unsigned short u16x8;

#define S_LEN 2048
#define DIM   4096
#define QKVN  6144
#define NHEAD 32
#define HDIM  128

typedef __attribute__((address_space(1))) unsigned int as1_u32;
typedef __attribute__((address_space(3))) unsigned int as3_u32;

__device__ __forceinline__ unsigned short f2bf(float f) {
  unsigned u = __builtin_bit_cast(unsigned, f);
  u += 0x7fffu + ((u >> 16) & 1u);
  return (unsigned short)(u >> 16);
}

__device__ __forceinline__ void gload_lds16(const void* g, void* l) {
  __builtin_amdgcn_global_load_lds(
      (as1_u32*)(unsigned long long)(uintptr_t)g,
      (as3_u32*)(unsigned int)(uintptr_t)l,
      16, 0, 0);
}

// Fused f32->bf16 conversion for all 5 inputs (one launch, grid-stride).
// At its HBM floor (432 MB ~ 69us). R15 lesson: in-GEMM f32 reads regress.
__global__ __launch_bounds__(256) void cvt5_kernel(const float* __restrict__ x,
                                                   const float* __restrict__ wq,
                                                   const float* __restrict__ wk,
                                                   const float* __restrict__ wv,
                                                   const float* __restrict__ wo,
                                                   ushort4* __restrict__ xb,
                                                   ushort4* __restrict__ wqkvb,
                                                   ushort4* __restrict__ wob) {
  const long N0 = 2097152;           // x  : 2048*4096/4
  const long N1 = N0 + 4194304;      // wq : 4096*4096/4
  const long N2 = N1 + 1048576;      // wk
  const long N3 = N2 + 1048576;      // wv
  const long N4 = N3 + 4194304;      // wo
  long idx = (long)blockIdx.x * 256 + threadIdx.x;
  long stride = (long)gridDim.x * 256;
  for (long i = idx; i < N4; i += stride) {
    const float4* s; ushort4* d; long o;
    if (i < N0)      { s = (const float4*)x;  d = xb;              o = i; }
    else if (i < N1) { s = (const float4*)wq; d = wqkvb;           o = i - N0; }
    else if (i < N2) { s = (const float4*)wk; d = wqkvb + 4194304; o = i - N1; }
    else if (i < N3) { s = (const float4*)wv; d = wqkvb + 5242880; o = i - N2; }
    else             { s = (const float4*)wo; d = wob;             o = i - N3; }
    float4 v = s[o];
    ushort4 r;
    r.x = f2bf(v.x); r.y = f2bf(v.y); r.z = f2bf(v.z); r.w = f2bf(v.w);
    d[o] = r;
  }
}

// Shared swizzled LDS fragment read: chunk ^= (row&7), both sides.
__device__ __forceinline__ bf16x8 fld(const char* half, int row, int chunk) {
  return *(const bf16x8*)(half + row * 128 + ((chunk ^ (row & 7)) << 4));
}

// ---- 256x192 2-phase GEMM, BK=64, 8 waves (2M x 4N), ONE barrier/phase --
// Phase = { ds_reads; stage; lgkm(0) [+vmcnt at P1]; BARRIER; MFMA }.
// At barrier-pass ALL waves' reads are drained -> next phase may overwrite
// the read buffer with no second barrier. Cross-wave overlap preserved:
// next-phase reads of a fast wave overlap slow waves' MFMA.
// A 3x32K, B 2x24K = 144KB. vmcnt(7) at P1 drains A(t+1)+B(t+1) exactly.
__global__ __launch_bounds__(512, 2) void gemm8q(const bf16_t* __restrict__ A,
                                                 const bf16_t* __restrict__ B,
                                                 unsigned short* __restrict__ C,
                                                 int M, int N, int K, int nxt) {
  __shared__ char lds[147456];   // A 3x32K @0; B 2x24K @98304
  const int tid = threadIdx.x;
  const int lane = tid & 63, w = tid >> 6;
  const int wm = w >> 2, wn = w & 3;       // 2 M-waves x 4 N-waves
  const int lg = lane >> 4, lr = lane & 15;
  const int nwg = gridDim.x;
  const int orig = blockIdx.x;
  const int wgid = (orig & 7) * (nwg >> 3) + (orig >> 3);  // nwg % 8 == 0
  const int bx = wgid % nxt, by = wgid / nxt;
  const long rowA = (long)by * 256;
  const long rowB = (long)bx * 192;

  f32x4 acc[8][3];
  const f32x4 z4 = {0.f, 0.f, 0.f, 0.f};
#pragma unroll
  for (int i = 0; i < 8; ++i)
#pragma unroll
    for (int j = 0; j < 3; ++j) acc[i][j] = z4;

  const int r0 = tid >> 3, sl = tid & 7;
  const long xo  = (long)((sl ^ (r0 & 7)) << 3);
  const long aof = (rowA + r0) * (long)K + xo;
  const long bof = (rowB + r0) * (long)K + xo;
  const long j1  = (long)64 * K;
  const long h1  = (long)128 * K;
  const int ld0 = tid * 16, ld1 = (tid + 512) * 16, ld2 = (tid + 1024) * 16;

#define QSTG_A(K0, BUF3)                                                       \
  { char* hp = lds + (BUF3) * 32768;                                           \
    gload_lds16(A + aof + (K0),           hp + ld0);                           \
    gload_lds16(A + aof + j1 + (K0),      hp + ld1);                           \
    gload_lds16(A + aof + h1 + (K0),      hp + 16384 + ld0);                   \
    gload_lds16(A + aof + h1 + j1 + (K0), hp + 16384 + ld1); }
#define QSTG_B(K0, DBUF)                                                       \
  { char* bp = lds + 98304 + (DBUF) * 24576;                                   \
    gload_lds16(B + bof + (K0),          bp + ld0);                            \
    gload_lds16(B + bof + j1 + (K0),     bp + ld1);                            \
    gload_lds16(B + bof + 2 * j1 + (K0), bp + ld2); }

  const int nt = K >> 6;
  const int brow = wn * 48;

  // prologue: A(0),B(0),A(1),B(1) FIFO; vmcnt(7) -> tile0 landed.
  QSTG_A(0, 0);  QSTG_B(0, 0);
  QSTG_A(64, 1); QSTG_B(64, 1);
  asm volatile("s_waitcnt vmcnt(7)" ::: "memory");
  __builtin_amdgcn_s_barrier();

  bf16x8 af[8][2], bf_[3][2];

  for (int t = 0; t < nt; ++t) {
    const int a3 = t % 3, s3 = (t + 2) % 3, d = t & 1;
    const char* Ah = lds + a3 * 32768 + wm * 16384;
    const char* Br = lds + 98304 + d * 24576;
    const int k2 = (t + 2) << 6;
    // ---- P0: reads {B all, A m0-3}; stage A(t+2); lgkm(0); BAR; MFMA ----
#pragma unroll
    for (int n = 0; n < 3; ++n) {
      bf_[n][0] = fld(Br, brow + n * 16 + lr, lg);
      bf_[n][1] = fld(Br, brow + n * 16 + lr, 4 + lg);
    }
#pragma unroll
    for (int m = 0; m < 4; ++m) {
      af[m][0] = fld(Ah, m * 16 + lr, lg);
      af[m][1] = fld(Ah, m * 16 + lr, 4 + lg);
    }
    if (t + 2 < nt) QSTG_A(k2, s3);
    asm volatile("s_waitcnt lgkmcnt(0)" ::: "memory");
    __builtin_amdgcn_sched_barrier(0);
    __builtin_amdgcn_s_barrier();
    __builtin_amdgcn_s_setprio(1);
#pragma unroll
    for (int m = 0; m < 4; ++m)
#pragma unroll
      for (int n = 0; n < 3; ++n) {
        acc[m][n] = __builtin_amdgcn_mfma_f32_16x16x32_bf16(af[m][0], bf_[n][0], acc[m][n], 0, 0, 0);
        acc[m][n] = __builtin_amdgcn_mfma_f32_16x16x32_bf16(af[m][1], bf_[n][1], acc[m][n], 0, 0, 0);
      }
    __builtin_amdgcn_s_setprio(0);
    // ---- P1: reads {A m4-7}; stage B(t+2); lgkm(0)+vmcnt; BAR; MFMA ----
#pragma unroll
    for (int m = 4; m < 8; ++m) {
      af[m][0] = fld(Ah, m * 16 + lr, lg);
      af[m][1] = fld(Ah, m * 16 + lr, 4 + lg);
    }
    if (t + 2 < nt) QSTG_B(k2, d);
    asm volatile("s_waitcnt lgkmcnt(0)" ::: "memory");
    __builtin_amdgcn_sched_barrier(0);
    if (t + 2 < nt) {
      asm volatile("s_waitcnt vmcnt(7)" ::: "memory");   // t+1 landed
    } else {
      asm volatile("s_waitcnt vmcnt(0)" ::: "memory");
    }
    __builtin_amdgcn_s_barrier();
    __builtin_amdgcn_s_setprio(1);
#pragma unroll
    for (int m = 4; m < 8; ++m)
#pragma unroll
      for (int n = 0; n < 3; ++n) {
        acc[m][n] = __builtin_amdgcn_mfma_f32_16x16x32_bf16(af[m][0], bf_[n][0], acc[m][n], 0, 0, 0);
        acc[m][n] = __builtin_amdgcn_mfma_f32_16x16x32_bf16(af[m][1], bf_[n][1], acc[m][n], 0, 0, 0);
      }
    __builtin_amdgcn_s_setprio(0);
  }
#undef QSTG_A
#undef QSTG_B

  const long crow = rowA + wm * 128;
  const long ccol = rowB + wn * 48;
#pragma unroll
  for (int mf = 0; mf < 8; ++mf)
#pragma unroll
    for (int j = 0; j < 4; ++j) {
      long row = crow + mf * 16 + lg * 4 + j;
      unsigned short* cp = C + row * N + ccol + lr;
#pragma unroll
      for (int nf = 0; nf < 3; ++nf) cp[nf * 16] = f2bf(acc[mf][nf][j]);
    }
}

// ---- 256x128 2-phase GEMM, BK=64, 8 waves, ONE barrier/phase ------------
__global__ __launch_bounds__(512, 2) void gemm2p(const bf16_t* __restrict__ A,
                                                 const bf16_t* __restrict__ B,
                                                 float* __restrict__ C,
                                                 int M, int N, int K, int nxt) {
  __shared__ char lds[147456];
  const int tid = threadIdx.x;
  const int lane = tid & 63, w = tid >> 6;
  const int wm = w >> 1, wn = w & 1;       // 4 M-waves x 2 N-waves, 64x64
  const int lg = lane >> 4, lr = lane & 15;
  const int nwg = gridDim.x;
  const int orig = blockIdx.x;
  const int wgid = (orig & 7) * (nwg >> 3) + (orig >> 3);  // nwg % 8 == 0
  const int bx = wgid % nxt, by = wgid / nxt;
  const long rowA = (long)by * 256;
  const long rowB = (long)bx * 128;

  f32x4 acc[4][4];
  const f32x4 z4 = {0.f, 0.f, 0.f, 0.f};
#pragma unroll
  for (int i = 0; i < 4; ++i)
#pragma unroll
    for (int j = 0; j < 4; ++j) acc[i][j] = z4;

  const int r0 = tid >> 3, sl = tid & 7;
  const long xo  = (long)((sl ^ (r0 & 7)) << 3);
  const long aof = (rowA + r0) * (long)K + xo;
  const long bof = (rowB + r0) * (long)K + xo;
  const long r64 = (long)64 * K;

#define PSTG_A(K0, BUF)                                                        \
  { char* ap = lds + (BUF) * 32768;                                            \
    gload_lds16(A + aof + (K0),           ap + tid * 16);                      \
    gload_lds16(A + aof + r64 + (K0),     ap + (tid + 512) * 16);              \
    gload_lds16(A + aof + 2 * r64 + (K0), ap + (tid + 1024) * 16);             \
    gload_lds16(A + aof + 3 * r64 + (K0), ap + (tid + 1536) * 16); }
#define PSTG_B(K0, BUF)                                                        \
  { char* bp = lds + 98304 + (BUF) * 16384;                                    \
    gload_lds16(B + bof + (K0),       bp + tid * 16);                          \
    gload_lds16(B + bof + r64 + (K0), bp + (tid + 512) * 16); }

  const int nt = K >> 6;

  PSTG_A(0, 0); PSTG_B(0, 0); PSTG_A(64, 1); PSTG_B(64, 1);
  asm volatile("s_waitcnt vmcnt(6)" ::: "memory");
  __builtin_amdgcn_s_barrier();

  bf16x8 af[4][2], bf_[4][2];

  for (int t = 0; t < nt; ++t) {
    const int b3 = t % 3, s3 = (t + 2) % 3;
    const char* Ab = lds + b3 * 32768;
    const char* Bb = lds + 98304 + b3 * 16384;
    const int arow = wm * 64, brow = wn * 64;
    const int k2 = (t + 2) << 6;
    // ---- P0: reads {A all, B n0-1}; stage A(t+2); lgkm(0); BAR; MFMA ----
#pragma unroll
    for (int m = 0; m < 4; ++m) {
      af[m][0] = fld(Ab, arow + m * 16 + lr, lg);
      af[m][1] = fld(Ab, arow + m * 16 + lr, 4 + lg);
    }
#pragma unroll
    for (int n = 0; n < 2; ++n) {
      bf_[n][0] = fld(Bb, brow + n * 16 + lr, lg);
      bf_[n][1] = fld(Bb, brow + n * 16 + lr, 4 + lg);
    }
    if (t + 2 < nt) PSTG_A(k2, s3);
    asm volatile("s_waitcnt lgkmcnt(0)" ::: "memory");
    __builtin_amdgcn_sched_barrier(0);
    __builtin_amdgcn_s_barrier();
    __builtin_amdgcn_s_setprio(1);
#pragma unroll
    for (int m = 0; m < 4; ++m)
#pragma unroll
      for (int n = 0; n < 2; ++n) {
        acc[m][n] = __builtin_amdgcn_mfma_f32_16x16x32_bf16(af[m][0], bf_[n][0], acc[m][n], 0, 0, 0);
        acc[m][n] = __builtin_amdgcn_mfma_f32_16x16x32_bf16(af[m][1], bf_[n][1], acc[m][n], 0, 0, 0);
      }
    __builtin_amdgcn_s_setprio(0);
    // ---- P1: reads {B n2-3}; stage B(t+2); lgkm(0)+vmcnt; BAR; MFMA ----
#pragma unroll
    for (int n = 2; n < 4; ++n) {
      bf_[n][0] = fld(Bb, brow + n * 16 + lr, lg);
      bf_[n][1] = fld(Bb, brow + n * 16 + lr, 4 + lg);
    }
    if (t + 2 < nt) PSTG_B(k2, s3);
    asm volatile("s_waitcnt lgkmcnt(0)" ::: "memory");
    __builtin_amdgcn_sched_barrier(0);
    if (t + 2 < nt) {
      asm volatile("s_waitcnt vmcnt(6)" ::: "memory");
    } else {
      asm volatile("s_waitcnt vmcnt(0)" ::: "memory");
    }
    __builtin_amdgcn_s_barrier();
    __builtin_amdgcn_s_setprio(1);
#pragma unroll
    for (int m = 0; m < 4; ++m)
#pragma unroll
      for (int n = 2; n < 4; ++n) {
        acc[m][n] = __builtin_amdgcn_mfma_f32_16x16x32_bf16(af[m][0], bf_[n][0], acc[m][n], 0, 0, 0);
        acc[m][n] = __builtin_amdgcn_mfma_f32_16x16x32_bf16(af[m][1], bf_[n][1], acc[m][n], 0, 0, 0);
      }
    __builtin_amdgcn_s_setprio(0);
  }
#undef PSTG_A
#undef PSTG_B

  const long crow = rowA + wm * 64;
  const long ccol = rowB + wn * 64;
#pragma unroll
  for (int mf = 0; mf < 4; ++mf)
#pragma unroll
    for (int j = 0; j < 4; ++j) {
      long row = crow + mf * 16 + lg * 4 + j;
      float* cp = C + row * N + ccol + lr;
#pragma unroll
      for (int nf = 0; nf < 4; ++nf) cp[nf * 16] = acc[mf][nf][j];
    }
}

// Merged prep: blocks [0,1024) = V transpose; blocks [1024, 21504) = RoPE.
__global__ __launch_bounds__(256) void prep_kernel(bf16_t* __restrict__ qkv,
                                                   bf16_t* __restrict__ vT,
                                                   const float* __restrict__ cosb,
                                                   const float* __restrict__ sinb) {
  const int bid = blockIdx.x;
  if (bid < 1024) {
    const int kh = bid & 7;
    const int hd = threadIdx.x & 127;
    const int s0 = (bid >> 3) * 16 + (threadIdx.x >> 7) * 8;
    u16x8 v;
#pragma unroll
    for (int e = 0; e < 8; ++e)
      v[e] = *(const unsigned short*)(qkv + (long)(s0 + e) * QKVN + 5120 + kh * HDIM + hd);
    *(u16x8*)(vT + ((long)kh * HDIM + hd) * S_LEN + s0) = v;
  } else {
    int t = (bid - 1024) * 256 + threadIdx.x;
    int i  = t & 63;
    int sh = t >> 6;
    int hh = sh % 40;
    int s  = sh / 40;
    int col2 = (hh < 32) ? (hh * 64 + i) : (2048 + (hh - 32) * 64 + i);
    unsigned int* p = (unsigned int*)qkv + (long)s * (QKVN / 2) + col2;
    unsigned int v = *p;
    float tr = __builtin_bit_cast(float, (v & 0xffffu) << 16);
    float ti = __builtin_bit_cast(float, v & 0xffff0000u);
    float c  = cosb[s * 64 + i];
    float sn = sinb[s * 64 + i];
    float orr = tr * c - ti * sn;
    float oi  = tr * sn + ti * c;
    *p = (unsigned int)f2bf(orr) | ((unsigned int)f2bf(oi) << 16);
  }
}

// Flash attention (R16-verified): XCD kh-affinity remap, K/V dbuf,
// per-lane plsum, __any-gated max reduce.
__global__ __launch_bounds__(512) void attn_kernel(const bf16_t* __restrict__ qkv,
                                                   const bf16_t* __restrict__ vT,
                                                   unsigned short* __restrict__ ob) {
  __shared__ bf16_t Kt[2][64 * 128];
  __shared__ bf16_t Vt[2][128 * 64];
  __shared__ bf16_t Pl[8 * 16 * 64];
  const int b   = blockIdx.x;
  const int xcd = b & 7, bidx = b >> 3;
  const int h   = xcd * 4 + (bidx & 3);
  const int qi  = 15 - (bidx >> 2);
  const int qb  = qi * 128;
  const int kh  = h >> 2;
  const int tid = threadIdx.x, lane = tid & 63, w = tid >> 6;
  const int lg = lane >> 4, lr = lane & 15;
  const int qrow0 = qb + w * 16;

  bf16x8 qf[4];
  const bf16_t* qptr = qkv + (long)(qrow0 + lr) * QKVN + h * HDIM + lg * 8;
#pragma unroll
  for (int kk = 0; kk < 4; ++kk) qf[kk] = *(const bf16x8*)(qptr + kk * 32);

  const f32x4 z4 = {0.f, 0.f, 0.f, 0.f};
  f32x4 oacc[8];
#pragma unroll
  for (int c = 0; c < 8; ++c) oacc[c] = z4;
  float m[4]     = {-1e30f, -1e30f, -1e30f, -1e30f};
  float plsum[4] = {0.f, 0.f, 0.f, 0.f};

  char* PlB = (char*)Pl + w * 2048;
  const float SCL2 = 0.08838834764831845f * 1.44269504088896f;
  const int ntiles = 2 * qi + 2;
  const int wqmax = qrow0 + 15;

#define STAGE_KV(T, BUF)                                                       \
  {                                                                            \
    const int kvs = (T) * 64;                                                  \
    _Pragma("unroll")                                                          \
    for (int it = 0; it < 2; ++it) {                                           \
      int cch = tid + it * 512;                                                \
      int r = cch >> 4, c = cch & 15;                                          \
      gload_lds16(qkv + (long)(kvs + r) * QKVN + 4096 + kh * HDIM              \
                      + ((c ^ (r & 7)) * 8),                                   \
                  (char*)Kt[BUF] + cch * 16);                                  \
    }                                                                          \
    _Pragma("unroll")                                                          \
    for (int it = 0; it < 2; ++it) {                                           \
      int cch = tid + it * 512;                                                \
      int hd2 = cch >> 3, c = cch & 7;                                         \
      gload_lds16(vT + ((long)kh * HDIM + hd2) * S_LEN + kvs                   \
                      + ((c ^ (hd2 & 7)) * 8),                                 \
                  (char*)Vt[BUF] + cch * 16);                                  \
    }                                                                          \
  }

  STAGE_KV(0, 0);
  STAGE_KV(1, 1);
  asm volatile("s_waitcnt vmcnt(4)" ::: "memory");
  __builtin_amdgcn_s_barrier();

  for (int t = 0; t < ntiles; ++t) {
    const int kv0 = t * 64;
    const int d = t & 1;
    if (kv0 <= wqmax) {
      char* KtB = (char*)Kt[d];
      char* VtB = (char*)Vt[d];

      f32x4 sf[4];
#pragma unroll
      for (int f = 0; f < 4; ++f) {
        f32x4 a = z4;
        int n = f * 16 + lr;
        int rb = n * 256, sw = (n & 7) << 4;
#pragma unroll
        for (int kk = 0; kk < 4; ++kk) {
          bf16x8 kf = *(const bf16x8*)(KtB + rb + (((kk * 4 + lg) * 16) ^ sw));
          a = __builtin_amdgcn_mfma_f32_16x16x32_bf16(qf[kk], kf, a, 0, 0, 0);
        }
        sf[f] = a;
      }

      float sv[4][4], lmax[4];
      if (kv0 + 63 <= qrow0) {
#pragma unroll
        for (int j = 0; j < 4; ++j) {
#pragma unroll
          for (int f = 0; f < 4; ++f) sv[j][f] = sf[f][j] * SCL2;
          lmax[j] = fmaxf(fmaxf(sv[j][0], sv[j][1]), fmaxf(sv[j][2], sv[j][3]));
        }
      } else {
#pragma unroll
        for (int j = 0; j < 4; ++j) {
          int qrow = qrow0 + lg * 4 + j;
#pragma unroll
          for (int f = 0; f < 4; ++f) {
            float s = sf[f][j] * SCL2;
            if (kv0 + f * 16 + lr > qrow) s = -1e9f;
            sv[j][f] = s;
          }
          lmax[j] = fmaxf(fmaxf(sv[j][0], sv[j][1]), fmaxf(sv[j][2], sv[j][3]));
        }
      }
      float g = fmaxf(fmaxf(lmax[0] - m[0], lmax[1] - m[1]),
                      fmaxf(lmax[2] - m[2], lmax[3] - m[3]));
      if (__any(g > 0.f)) {
#pragma unroll
        for (int j = 0; j < 4; ++j) {
          float t0 = lmax[j];
          t0 = fmaxf(t0, __shfl_xor(t0, 1));
          t0 = fmaxf(t0, __shfl_xor(t0, 2));
          t0 = fmaxf(t0, __shfl_xor(t0, 4));
          t0 = fmaxf(t0, __shfl_xor(t0, 8));
          float mn = fmaxf(m[j], t0);
          float sc;
          asm("v_exp_f32 %0, %1" : "=v"(sc) : "v"(m[j] - mn));
          plsum[j] *= sc;
          m[j] = mn;
#pragma unroll
          for (int c = 0; c < 8; ++c) oacc[c][j] *= sc;
        }
      }
#pragma unroll
      for (int j = 0; j < 4; ++j) {
        float p[4];
#pragma unroll
        for (int f = 0; f < 4; ++f)
          asm("v_exp_f32 %0, %1" : "=v"(p[f]) : "v"(sv[j][f] - m[j]));
        plsum[j] += (p[0] + p[1]) + (p[2] + p[3]);
        int row = lg * 4 + j;
        int swp = (row & 7) << 4;
#pragma unroll
        for (int f = 0; f < 4; ++f)
          *(unsigned short*)(PlB + row * 128 + (((f * 16 + lr) * 2) ^ swp)) = f2bf(p[f]);
      }

      bf16x8 pfr[2];
#pragma unroll
      for (int kk = 0; kk < 2; ++kk)
        pfr[kk] = *(const bf16x8*)(PlB + lr * 128 + (((kk * 4 + lg) * 16) ^ ((lr & 7) << 4)));
#pragma unroll
      for (int c = 0; c < 8; ++c) {
        int hd = c * 16 + lr;
        int rb = hd * 128, sw = (hd & 7) << 4;
#pragma unroll
        for (int kk = 0; kk < 2; ++kk) {
          bf16x8 vf = *(const bf16x8*)(VtB + rb + (((kk * 4 + lg) * 16) ^ sw));
          oacc[c] = __builtin_amdgcn_mfma_f32_16x16x32_bf16(pfr[kk], vf, oacc[c], 0, 0, 0);
        }
      }
    }
    __builtin_amdgcn_s_barrier();
    if (t + 2 < ntiles) {
      STAGE_KV(t + 2, d);
      asm volatile("s_waitcnt vmcnt(4)" ::: "memory");
    } else {
      asm volatile("s_waitcnt vmcnt(0)" ::: "memory");
    }
    __builtin_amdgcn_s_barrier();
  }
#undef STAGE_KV

  float rl[4];
#pragma unroll
  for (int j = 0; j < 4; ++j) {
    float s = plsum[j];
    s += __shfl_xor(s, 1);
    s += __shfl_xor(s, 2);
    s += __shfl_xor(s, 4);
    s += __shfl_xor(s, 8);
    rl[j] = 1.f / s;
  }
#pragma unroll
  for (int c = 0; c < 8; ++c)
#pragma unroll
    for (int j = 0; j < 4; ++j) {
      long row = qrow0 + lg * 4 + j;
      ob[row * 4096 + h * 128 + c * 16 + lr] = f2bf(oacc[c][j] * rl[j]);
    }
}

extern "C" void kernel_launch(void* const* d_in, const int* in_sizes, int n_in,
                              void* d_out, int out_size, void* d_ws, size_t ws_size,
                              hipStream_t stream) {
  const float* x  = (const float*)d_in[0];
  const float* wq = (const float*)d_in[1];
  const float* wk = (const float*)d_in[2];
  const float* wv = (const float*)d_in[3];
  const float* wo = (const float*)d_in[4];
  const float* fc = (const float*)d_in[5];
  const float* fs = (const float*)d_in[6];

  char* ws = (char*)d_ws;
  bf16_t* xb    = (bf16_t*)(ws + 0);          // 2048x4096 (dead after gemm1)
  bf16_t* wqkvb = (bf16_t*)(ws + 16777216);   // 6144x4096
  bf16_t* wob   = (bf16_t*)(ws + 67108864);   // 4096x4096
  bf16_t* qkv   = (bf16_t*)(ws + 100663296);  // 2048x6144
  bf16_t* ob    = (bf16_t*)(ws + 125829120);  // 2048x4096
  bf16_t* vT    = (bf16_t*)(ws + 0);          // 8x128x2048 (4 MB, reuses xb)

  cvt5_kernel<<<2048, 256, 0, stream>>>(x, wq, wk, wv, wo,
                                        (ushort4*)xb, (ushort4*)wqkvb, (ushort4*)wob);

  gemm8q<<<256, 512, 0, stream>>>(xb, wqkvb, (unsigned short*)qkv,
                                  2048, 6144, 4096, 32);
  prep_kernel<<<21504, 256, 0, stream>>>(qkv, vT, fc, fs);
  attn_kernel<<<512, 512, 0, stream>>>(qkv, vT, (unsigned short*)ob);
  gemm2p<<<256, 512, 0, stream>>>(ob, wob, (float*)d_out, 2048, 4096, 4096, 32);
}

// Round 19
// 291.731 us; speedup vs baseline: 1.1375x; 1.0269x over previous
//
#include <hip/hip_runtime.h>
#include <hip/hip_bf16.h>
#include <stdint.h>

typedef __bf16 bf16_t;
typedef __attribute__((ext_vector_type(8))) __bf16 bf16x8;
typedef __attribute__((ext_vector_type(4))) float f32x4;
typedef __attribute__((ext_vector_type(8))) unsigned short u16x8;

#define S_LEN 2048
#define DIM   4096
#define QKVN  6144
#define NHEAD 32
#define HDIM  128

typedef __attribute__((address_space(1))) unsigned int as1_u32;
typedef __attribute__((address_space(3))) unsigned int as3_u32;

__device__ __forceinline__ unsigned short f2bf(float f) {
  unsigned u = __builtin_bit_cast(unsigned, f);
  u += 0x7fffu + ((u >> 16) & 1u);
  return (unsigned short)(u >> 16);
}

__device__ __forceinline__ void gload_lds16(const void* g, void* l) {
  __builtin_amdgcn_global_load_lds(
      (as1_u32*)(unsigned long long)(uintptr_t)g,
      (as3_u32*)(unsigned int)(uintptr_t)l,
      16, 0, 0);
}

// Fused f32->bf16 conversion for all 5 inputs (one launch, grid-stride).
// At its HBM floor (432 MB ~ 69us). R15 lesson: in-GEMM f32 reads regress.
__global__ __launch_bounds__(256) void cvt5_kernel(const float* __restrict__ x,
                                                   const float* __restrict__ wq,
                                                   const float* __restrict__ wk,
                                                   const float* __restrict__ wv,
                                                   const float* __restrict__ wo,
                                                   ushort4* __restrict__ xb,
                                                   ushort4* __restrict__ wqkvb,
                                                   ushort4* __restrict__ wob) {
  const long N0 = 2097152;           // x  : 2048*4096/4
  const long N1 = N0 + 4194304;      // wq : 4096*4096/4
  const long N2 = N1 + 1048576;      // wk
  const long N3 = N2 + 1048576;      // wv
  const long N4 = N3 + 4194304;      // wo
  long idx = (long)blockIdx.x * 256 + threadIdx.x;
  long stride = (long)gridDim.x * 256;
  for (long i = idx; i < N4; i += stride) {
    const float4* s; ushort4* d; long o;
    if (i < N0)      { s = (const float4*)x;  d = xb;              o = i; }
    else if (i < N1) { s = (const float4*)wq; d = wqkvb;           o = i - N0; }
    else if (i < N2) { s = (const float4*)wk; d = wqkvb + 4194304; o = i - N1; }
    else if (i < N3) { s = (const float4*)wv; d = wqkvb + 5242880; o = i - N2; }
    else             { s = (const float4*)wo; d = wob;             o = i - N3; }
    float4 v = s[o];
    ushort4 r;
    r.x = f2bf(v.x); r.y = f2bf(v.y); r.z = f2bf(v.z); r.w = f2bf(v.w);
    d[o] = r;
  }
}

// Shared swizzled LDS fragment read: chunk ^= (row&7), both sides.
__device__ __forceinline__ bf16x8 fld(const char* half, int row, int chunk) {
  return *(const bf16x8*)(half + row * 128 + ((chunk ^ (row & 7)) << 4));
}

// ---- 256x192 2-phase GEMM (R18: 95us, 46% MfmaUtil) + FUSED EPILOGUE ----
// Epilogue applies RoPE to q/k columns (pair = adjacent lanes, shfl_xor)
// and writes v columns transposed into vT (skipping the qkv copy).
// Each 16-col group is wave-uniform in head-type (16 | 128 boundaries).
__global__ __launch_bounds__(512, 2) void gemm8q(const bf16_t* __restrict__ A,
                                                 const bf16_t* __restrict__ B,
                                                 unsigned short* __restrict__ C,
                                                 const float* __restrict__ fc,
                                                 const float* __restrict__ fs,
                                                 bf16_t* __restrict__ vT,
                                                 int M, int N, int K, int nxt) {
  __shared__ char lds[147456];   // A 3x32K @0; B 2x24K @98304
  const int tid = threadIdx.x;
  const int lane = tid & 63, w = tid >> 6;
  const int wm = w >> 2, wn = w & 3;       // 2 M-waves x 4 N-waves
  const int lg = lane >> 4, lr = lane & 15;
  const int nwg = gridDim.x;
  const int orig = blockIdx.x;
  const int wgid = (orig & 7) * (nwg >> 3) + (orig >> 3);  // nwg % 8 == 0
  const int bx = wgid % nxt, by = wgid / nxt;
  const long rowA = (long)by * 256;
  const long rowB = (long)bx * 192;

  f32x4 acc[8][3];
  const f32x4 z4 = {0.f, 0.f, 0.f, 0.f};
#pragma unroll
  for (int i = 0; i < 8; ++i)
#pragma unroll
    for (int j = 0; j < 3; ++j) acc[i][j] = z4;

  const int r0 = tid >> 3, sl = tid & 7;
  const long xo  = (long)((sl ^ (r0 & 7)) << 3);
  const long aof = (rowA + r0) * (long)K + xo;
  const long bof = (rowB + r0) * (long)K + xo;
  const long j1  = (long)64 * K;
  const long h1  = (long)128 * K;
  const int ld0 = tid * 16, ld1 = (tid + 512) * 16, ld2 = (tid + 1024) * 16;

#define QSTG_A(K0, BUF3)                                                       \
  { char* hp = lds + (BUF3) * 32768;                                           \
    gload_lds16(A + aof + (K0),           hp + ld0);                           \
    gload_lds16(A + aof + j1 + (K0),      hp + ld1);                           \
    gload_lds16(A + aof + h1 + (K0),      hp + 16384 + ld0);                   \
    gload_lds16(A + aof + h1 + j1 + (K0), hp + 16384 + ld1); }
#define QSTG_B(K0, DBUF)                                                       \
  { char* bp = lds + 98304 + (DBUF) * 24576;                                   \
    gload_lds16(B + bof + (K0),          bp + ld0);                            \
    gload_lds16(B + bof + j1 + (K0),     bp + ld1);                            \
    gload_lds16(B + bof + 2 * j1 + (K0), bp + ld2); }

  const int nt = K >> 6;
  const int brow = wn * 48;

  // prologue: A(0),B(0),A(1),B(1) FIFO; vmcnt(7) -> tile0 landed.
  QSTG_A(0, 0);  QSTG_B(0, 0);
  QSTG_A(64, 1); QSTG_B(64, 1);
  asm volatile("s_waitcnt vmcnt(7)" ::: "memory");
  __builtin_amdgcn_s_barrier();

  bf16x8 af[8][2], bf_[3][2];

  for (int t = 0; t < nt; ++t) {
    const int a3 = t % 3, s3 = (t + 2) % 3, d = t & 1;
    const char* Ah = lds + a3 * 32768 + wm * 16384;
    const char* Br = lds + 98304 + d * 24576;
    const int k2 = (t + 2) << 6;
    // ---- P0: reads {B all, A m0-3}; stage A(t+2); lgkm(0); BAR; MFMA ----
#pragma unroll
    for (int n = 0; n < 3; ++n) {
      bf_[n][0] = fld(Br, brow + n * 16 + lr, lg);
      bf_[n][1] = fld(Br, brow + n * 16 + lr, 4 + lg);
    }
#pragma unroll
    for (int m = 0; m < 4; ++m) {
      af[m][0] = fld(Ah, m * 16 + lr, lg);
      af[m][1] = fld(Ah, m * 16 + lr, 4 + lg);
    }
    if (t + 2 < nt) QSTG_A(k2, s3);
    asm volatile("s_waitcnt lgkmcnt(0)" ::: "memory");
    __builtin_amdgcn_sched_barrier(0);
    __builtin_amdgcn_s_barrier();
    __builtin_amdgcn_s_setprio(1);
#pragma unroll
    for (int m = 0; m < 4; ++m)
#pragma unroll
      for (int n = 0; n < 3; ++n) {
        acc[m][n] = __builtin_amdgcn_mfma_f32_16x16x32_bf16(af[m][0], bf_[n][0], acc[m][n], 0, 0, 0);
        acc[m][n] = __builtin_amdgcn_mfma_f32_16x16x32_bf16(af[m][1], bf_[n][1], acc[m][n], 0, 0, 0);
      }
    __builtin_amdgcn_s_setprio(0);
    // ---- P1: reads {A m4-7}; stage B(t+2); lgkm(0)+vmcnt; BAR; MFMA ----
#pragma unroll
    for (int m = 4; m < 8; ++m) {
      af[m][0] = fld(Ah, m * 16 + lr, lg);
      af[m][1] = fld(Ah, m * 16 + lr, 4 + lg);
    }
    if (t + 2 < nt) QSTG_B(k2, d);
    asm volatile("s_waitcnt lgkmcnt(0)" ::: "memory");
    __builtin_amdgcn_sched_barrier(0);
    if (t + 2 < nt) {
      asm volatile("s_waitcnt vmcnt(7)" ::: "memory");   // t+1 landed
    } else {
      asm volatile("s_waitcnt vmcnt(0)" ::: "memory");
    }
    __builtin_amdgcn_s_barrier();
    __builtin_amdgcn_s_setprio(1);
#pragma unroll
    for (int m = 4; m < 8; ++m)
#pragma unroll
      for (int n = 0; n < 3; ++n) {
        acc[m][n] = __builtin_amdgcn_mfma_f32_16x16x32_bf16(af[m][0], bf_[n][0], acc[m][n], 0, 0, 0);
        acc[m][n] = __builtin_amdgcn_mfma_f32_16x16x32_bf16(af[m][1], bf_[n][1], acc[m][n], 0, 0, 0);
      }
    __builtin_amdgcn_s_setprio(0);
  }
#undef QSTG_A
#undef QSTG_B

  // ---- fused epilogue: RoPE (q/k) or transposed-V write ----
  const long crow = rowA + wm * 128;
  const long ccol = rowB + wn * 48;
#pragma unroll
  for (int nf = 0; nf < 3; ++nf) {
    const long cbase = ccol + nf * 16;          // wave-uniform
    const long col   = cbase + lr;
    if (cbase < 5120) {
      // q or k head: RoPE. pair = adjacent lanes (col even/odd = lr&1).
      const int i2 = (int)((col & 127) >> 1);
      const float sgn = (col & 1) ? 1.f : -1.f;
#pragma unroll
      for (int mf = 0; mf < 8; ++mf)
#pragma unroll
        for (int j = 0; j < 4; ++j) {
          long row = crow + mf * 16 + lg * 4 + j;
          float v = acc[mf][nf][j];
          float p = __shfl_xor(v, 1);
          float c = fc[row * 64 + i2];
          float sn = fs[row * 64 + i2];
          C[row * (long)N + col] = f2bf(v * c + sgn * p * sn);
        }
    } else {
      // v head: write transposed into vT[kh][hd][s] (skip qkv copy).
      const int kh = (int)((col - 5120) >> 7);
      const int hd = (int)(col & 127);
      bf16_t* vbase = vT + ((long)kh * HDIM + hd) * S_LEN;
#pragma unroll
      for (int mf = 0; mf < 8; ++mf) {
        long s0 = crow + mf * 16 + lg * 4;
        ushort4 w4;
        w4.x = f2bf(acc[mf][nf][0]);
        w4.y = f2bf(acc[mf][nf][1]);
        w4.z = f2bf(acc[mf][nf][2]);
        w4.w = f2bf(acc[mf][nf][3]);
        *(ushort4*)(vbase + s0) = w4;
      }
    }
  }
}

// ---- 256x128 2-phase GEMM, BK=64, 8 waves, ONE barrier/phase (R18) ------
__global__ __launch_bounds__(512, 2) void gemm2p(const bf16_t* __restrict__ A,
                                                 const bf16_t* __restrict__ B,
                                                 float* __restrict__ C,
                                                 int M, int N, int K, int nxt) {
  __shared__ char lds[147456];
  const int tid = threadIdx.x;
  const int lane = tid & 63, w = tid >> 6;
  const int wm = w >> 1, wn = w & 1;       // 4 M-waves x 2 N-waves, 64x64
  const int lg = lane >> 4, lr = lane & 15;
  const int nwg = gridDim.x;
  const int orig = blockIdx.x;
  const int wgid = (orig & 7) * (nwg >> 3) + (orig >> 3);  // nwg % 8 == 0
  const int bx = wgid % nxt, by = wgid / nxt;
  const long rowA = (long)by * 256;
  const long rowB = (long)bx * 128;

  f32x4 acc[4][4];
  const f32x4 z4 = {0.f, 0.f, 0.f, 0.f};
#pragma unroll
  for (int i = 0; i < 4; ++i)
#pragma unroll
    for (int j = 0; j < 4; ++j) acc[i][j] = z4;

  const int r0 = tid >> 3, sl = tid & 7;
  const long xo  = (long)((sl ^ (r0 & 7)) << 3);
  const long aof = (rowA + r0) * (long)K + xo;
  const long bof = (rowB + r0) * (long)K + xo;
  const long r64 = (long)64 * K;

#define PSTG_A(K0, BUF)                                                        \
  { char* ap = lds + (BUF) * 32768;                                            \
    gload_lds16(A + aof + (K0),           ap + tid * 16);                      \
    gload_lds16(A + aof + r64 + (K0),     ap + (tid + 512) * 16);              \
    gload_lds16(A + aof + 2 * r64 + (K0), ap + (tid + 1024) * 16);             \
    gload_lds16(A + aof + 3 * r64 + (K0), ap + (tid + 1536) * 16); }
#define PSTG_B(K0, BUF)                                                        \
  { char* bp = lds + 98304 + (BUF) * 16384;                                    \
    gload_lds16(B + bof + (K0),       bp + tid * 16);                          \
    gload_lds16(B + bof + r64 + (K0), bp + (tid + 512) * 16); }

  const int nt = K >> 6;

  PSTG_A(0, 0); PSTG_B(0, 0); PSTG_A(64, 1); PSTG_B(64, 1);
  asm volatile("s_waitcnt vmcnt(6)" ::: "memory");
  __builtin_amdgcn_s_barrier();

  bf16x8 af[4][2], bf_[4][2];

  for (int t = 0; t < nt; ++t) {
    const int b3 = t % 3, s3 = (t + 2) % 3;
    const char* Ab = lds + b3 * 32768;
    const char* Bb = lds + 98304 + b3 * 16384;
    const int arow = wm * 64, brow = wn * 64;
    const int k2 = (t + 2) << 6;
    // ---- P0: reads {A all, B n0-1}; stage A(t+2); lgkm(0); BAR; MFMA ----
#pragma unroll
    for (int m = 0; m < 4; ++m) {
      af[m][0] = fld(Ab, arow + m * 16 + lr, lg);
      af[m][1] = fld(Ab, arow + m * 16 + lr, 4 + lg);
    }
#pragma unroll
    for (int n = 0; n < 2; ++n) {
      bf_[n][0] = fld(Bb, brow + n * 16 + lr, lg);
      bf_[n][1] = fld(Bb, brow + n * 16 + lr, 4 + lg);
    }
    if (t + 2 < nt) PSTG_A(k2, s3);
    asm volatile("s_waitcnt lgkmcnt(0)" ::: "memory");
    __builtin_amdgcn_sched_barrier(0);
    __builtin_amdgcn_s_barrier();
    __builtin_amdgcn_s_setprio(1);
#pragma unroll
    for (int m = 0; m < 4; ++m)
#pragma unroll
      for (int n = 0; n < 2; ++n) {
        acc[m][n] = __builtin_amdgcn_mfma_f32_16x16x32_bf16(af[m][0], bf_[n][0], acc[m][n], 0, 0, 0);
        acc[m][n] = __builtin_amdgcn_mfma_f32_16x16x32_bf16(af[m][1], bf_[n][1], acc[m][n], 0, 0, 0);
      }
    __builtin_amdgcn_s_setprio(0);
    // ---- P1: reads {B n2-3}; stage B(t+2); lgkm(0)+vmcnt; BAR; MFMA ----
#pragma unroll
    for (int n = 2; n < 4; ++n) {
      bf_[n][0] = fld(Bb, brow + n * 16 + lr, lg);
      bf_[n][1] = fld(Bb, brow + n * 16 + lr, 4 + lg);
    }
    if (t + 2 < nt) PSTG_B(k2, s3);
    asm volatile("s_waitcnt lgkmcnt(0)" ::: "memory");
    __builtin_amdgcn_sched_barrier(0);
    if (t + 2 < nt) {
      asm volatile("s_waitcnt vmcnt(6)" ::: "memory");
    } else {
      asm volatile("s_waitcnt vmcnt(0)" ::: "memory");
    }
    __builtin_amdgcn_s_barrier();
    __builtin_amdgcn_s_setprio(1);
#pragma unroll
    for (int m = 0; m < 4; ++m)
#pragma unroll
      for (int n = 2; n < 4; ++n) {
        acc[m][n] = __builtin_amdgcn_mfma_f32_16x16x32_bf16(af[m][0], bf_[n][0], acc[m][n], 0, 0, 0);
        acc[m][n] = __builtin_amdgcn_mfma_f32_16x16x32_bf16(af[m][1], bf_[n][1], acc[m][n], 0, 0, 0);
      }
    __builtin_amdgcn_s_setprio(0);
  }
#undef PSTG_A
#undef PSTG_B

  const long crow = rowA + wm * 64;
  const long ccol = rowB + wn * 64;
#pragma unroll
  for (int mf = 0; mf < 4; ++mf)
#pragma unroll
    for (int j = 0; j < 4; ++j) {
      long row = crow + mf * 16 + lg * 4 + j;
      float* cp = C + row * N + ccol + lr;
#pragma unroll
      for (int nf = 0; nf < 4; ++nf) cp[nf * 16] = acc[mf][nf][j];
    }
}

// Flash attention (R16-verified): XCD kh-affinity remap, K/V dbuf,
// per-lane plsum, __any-gated max reduce.
__global__ __launch_bounds__(512) void attn_kernel(const bf16_t* __restrict__ qkv,
                                                   const bf16_t* __restrict__ vT,
                                                   unsigned short* __restrict__ ob) {
  __shared__ bf16_t Kt[2][64 * 128];
  __shared__ bf16_t Vt[2][128 * 64];
  __shared__ bf16_t Pl[8 * 16 * 64];
  const int b   = blockIdx.x;
  const int xcd = b & 7, bidx = b >> 3;
  const int h   = xcd * 4 + (bidx & 3);
  const int qi  = 15 - (bidx >> 2);
  const int qb  = qi * 128;
  const int kh  = h >> 2;
  const int tid = threadIdx.x, lane = tid & 63, w = tid >> 6;
  const int lg = lane >> 4, lr = lane & 15;
  const int qrow0 = qb + w * 16;

  bf16x8 qf[4];
  const bf16_t* qptr = qkv + (long)(qrow0 + lr) * QKVN + h * HDIM + lg * 8;
#pragma unroll
  for (int kk = 0; kk < 4; ++kk) qf[kk] = *(const bf16x8*)(qptr + kk * 32);

  const f32x4 z4 = {0.f, 0.f, 0.f, 0.f};
  f32x4 oacc[8];
#pragma unroll
  for (int c = 0; c < 8; ++c) oacc[c] = z4;
  float m[4]     = {-1e30f, -1e30f, -1e30f, -1e30f};
  float plsum[4] = {0.f, 0.f, 0.f, 0.f};

  char* PlB = (char*)Pl + w * 2048;
  const float SCL2 = 0.08838834764831845f * 1.44269504088896f;
  const int ntiles = 2 * qi + 2;
  const int wqmax = qrow0 + 15;

#define STAGE_KV(T, BUF)                                                       \
  {                                                                            \
    const int kvs = (T) * 64;                                                  \
    _Pragma("unroll")                                                          \
    for (int it = 0; it < 2; ++it) {                                           \
      int cch = tid + it * 512;                                                \
      int r = cch >> 4, c = cch & 15;                                          \
      gload_lds16(qkv + (long)(kvs + r) * QKVN + 4096 + kh * HDIM              \
                      + ((c ^ (r & 7)) * 8),                                   \
                  (char*)Kt[BUF] + cch * 16);                                  \
    }                                                                          \
    _Pragma("unroll")                                                          \
    for (int it = 0; it < 2; ++it) {                                           \
      int cch = tid + it * 512;                                                \
      int hd2 = cch >> 3, c = cch & 7;                                         \
      gload_lds16(vT + ((long)kh * HDIM + hd2) * S_LEN + kvs                   \
                      + ((c ^ (hd2 & 7)) * 8),                                 \
                  (char*)Vt[BUF] + cch * 16);                                  \
    }                                                                          \
  }

  STAGE_KV(0, 0);
  STAGE_KV(1, 1);
  asm volatile("s_waitcnt vmcnt(4)" ::: "memory");
  __builtin_amdgcn_s_barrier();

  for (int t = 0; t < ntiles; ++t) {
    const int kv0 = t * 64;
    const int d = t & 1;
    if (kv0 <= wqmax) {
      char* KtB = (char*)Kt[d];
      char* VtB = (char*)Vt[d];

      f32x4 sf[4];
#pragma unroll
      for (int f = 0; f < 4; ++f) {
        f32x4 a = z4;
        int n = f * 16 + lr;
        int rb = n * 256, sw = (n & 7) << 4;
#pragma unroll
        for (int kk = 0; kk < 4; ++kk) {
          bf16x8 kf = *(const bf16x8*)(KtB + rb + (((kk * 4 + lg) * 16) ^ sw));
          a = __builtin_amdgcn_mfma_f32_16x16x32_bf16(qf[kk], kf, a, 0, 0, 0);
        }
        sf[f] = a;
      }

      float sv[4][4], lmax[4];
      if (kv0 + 63 <= qrow0) {
#pragma unroll
        for (int j = 0; j < 4; ++j) {
#pragma unroll
          for (int f = 0; f < 4; ++f) sv[j][f] = sf[f][j] * SCL2;
          lmax[j] = fmaxf(fmaxf(sv[j][0], sv[j][1]), fmaxf(sv[j][2], sv[j][3]));
        }
      } else {
#pragma unroll
        for (int j = 0; j < 4; ++j) {
          int qrow = qrow0 + lg * 4 + j;
#pragma unroll
          for (int f = 0; f < 4; ++f) {
            float s = sf[f][j] * SCL2;
            if (kv0 + f * 16 + lr > qrow) s = -1e9f;
            sv[j][f] = s;
          }
          lmax[j] = fmaxf(fmaxf(sv[j][0], sv[j][1]), fmaxf(sv[j][2], sv[j][3]));
        }
      }
      float g = fmaxf(fmaxf(lmax[0] - m[0], lmax[1] - m[1]),
                      fmaxf(lmax[2] - m[2], lmax[3] - m[3]));
      if (__any(g > 0.f)) {
#pragma unroll
        for (int j = 0; j < 4; ++j) {
          float t0 = lmax[j];
          t0 = fmaxf(t0, __shfl_xor(t0, 1));
          t0 = fmaxf(t0, __shfl_xor(t0, 2));
          t0 = fmaxf(t0, __shfl_xor(t0, 4));
          t0 = fmaxf(t0, __shfl_xor(t0, 8));
          float mn = fmaxf(m[j], t0);
          float sc;
          asm("v_exp_f32 %0, %1" : "=v"(sc) : "v"(m[j] - mn));
          plsum[j] *= sc;
          m[j] = mn;
#pragma unroll
          for (int c = 0; c < 8; ++c) oacc[c][j] *= sc;
        }
      }
#pragma unroll
      for (int j = 0; j < 4; ++j) {
        float p[4];
#pragma unroll
        for (int f = 0; f < 4; ++f)
          asm("v_exp_f32 %0, %1" : "=v"(p[f]) : "v"(sv[j][f] - m[j]));
        plsum[j] += (p[0] + p[1]) + (p[2] + p[3]);
        int row = lg * 4 + j;
        int swp = (row & 7) << 4;
#pragma unroll
        for (int f = 0; f < 4; ++f)
          *(unsigned short*)(PlB + row * 128 + (((f * 16 + lr) * 2) ^ swp)) = f2bf(p[f]);
      }

      bf16x8 pfr[2];
#pragma unroll
      for (int kk = 0; kk < 2; ++kk)
        pfr[kk] = *(const bf16x8*)(PlB + lr * 128 + (((kk * 4 + lg) * 16) ^ ((lr & 7) << 4)));
#pragma unroll
      for (int c = 0; c < 8; ++c) {
        int hd = c * 16 + lr;
        int rb = hd * 128, sw = (hd & 7) << 4;
#pragma unroll
        for (int kk = 0; kk < 2; ++kk) {
          bf16x8 vf = *(const bf16x8*)(VtB + rb + (((kk * 4 + lg) * 16) ^ sw));
          oacc[c] = __builtin_amdgcn_mfma_f32_16x16x32_bf16(pfr[kk], vf, oacc[c], 0, 0, 0);
        }
      }
    }
    __builtin_amdgcn_s_barrier();
    if (t + 2 < ntiles) {
      STAGE_KV(t + 2, d);
      asm volatile("s_waitcnt vmcnt(4)" ::: "memory");
    } else {
      asm volatile("s_waitcnt vmcnt(0)" ::: "memory");
    }
    __builtin_amdgcn_s_barrier();
  }
#undef STAGE_KV

  float rl[4];
#pragma unroll
  for (int j = 0; j < 4; ++j) {
    float s = plsum[j];
    s += __shfl_xor(s, 1);
    s += __shfl_xor(s, 2);
    s += __shfl_xor(s, 4);
    s += __shfl_xor(s, 8);
    rl[j] = 1.f / s;
  }
#pragma unroll
  for (int c = 0; c < 8; ++c)
#pragma unroll
    for (int j = 0; j < 4; ++j) {
      long row = qrow0 + lg * 4 + j;
      ob[row * 4096 + h * 128 + c * 16 + lr] = f2bf(oacc[c][j] * rl[j]);
    }
}

extern "C" void kernel_launch(void* const* d_in, const int* in_sizes, int n_in,
                              void* d_out, int out_size, void* d_ws, size_t ws_size,
                              hipStream_t stream) {
  const float* x  = (const float*)d_in[0];
  const float* wq = (const float*)d_in[1];
  const float* wk = (const float*)d_in[2];
  const float* wv = (const float*)d_in[3];
  const float* wo = (const float*)d_in[4];
  const float* fc = (const float*)d_in[5];
  const float* fs = (const float*)d_in[6];

  char* ws = (char*)d_ws;
  bf16_t* xb    = (bf16_t*)(ws + 0);          // 2048x4096 (dead after gemm1)
  bf16_t* wqkvb = (bf16_t*)(ws + 16777216);   // 6144x4096
  bf16_t* wob   = (bf16_t*)(ws + 67108864);   // 4096x4096
  bf16_t* qkv   = (bf16_t*)(ws + 100663296);  // 2048x6144
  bf16_t* ob    = (bf16_t*)(ws + 125829120);  // 2048x4096
  bf16_t* vT    = (bf16_t*)(ws + 142606336);  // 8x128x2048 (4 MB)

  cvt5_kernel<<<2048, 256, 0, stream>>>(x, wq, wk, wv, wo,
                                        (ushort4*)xb, (ushort4*)wqkvb, (ushort4*)wob);

  gemm8q<<<256, 512, 0, stream>>>(xb, wqkvb, (unsigned short*)qkv, fc, fs, vT,
                                  2048, 6144, 4096, 32);
  attn_kernel<<<512, 512, 0, stream>>>(qkv, vT, (unsigned short*)ob);
  gemm2p<<<256, 512, 0, stream>>>(ob, wob, (float*)d_out, 2048, 4096, 4096, 32);
}